// Round 1
// baseline (1724.381 us; speedup 1.0000x reference)
//
#include <hip/hip_runtime.h>
#include <hip/hip_bf16.h>
#include <math.h>

// Problem constants (Gemma3n attention block)
#define BB 2
#define SS 2048
#define HIDD 2048
#define NH 8
#define NKVH 2
#define HD 256
#define SWIN 512
#define QSCALAR 256.0f
#define LEPS 1e-6f
#define SCAP 30.0f

// ---------------------------------------------------------------------------
// GEMM: C[M,N] = A[M,K] @ W[N,K]^T, N split into up to 3 column groups
// (used for fused QKV projection and for the output projection).
// BM=BN=128, BK=16, 256 threads, 8x8 micro-tile with strided halves so that
// LDS reads are broadcast (A) or 2-way (B) -> conflict-free per m136.
// ---------------------------------------------------------------------------
__global__ __launch_bounds__(256) void gemm_nt(
    const float* __restrict__ A,
    const float* __restrict__ W0, const float* __restrict__ W1, const float* __restrict__ W2,
    float* __restrict__ C0, float* __restrict__ C1, float* __restrict__ C2,
    int n0, int n1, int n2, int K)
{
    __shared__ float As[16][132];   // K-major: As[kk][m]
    __shared__ float Bs[16][132];

    const int tid = (int)threadIdx.x;
    const int tx = tid & 15, ty = tid >> 4;
    const int row0 = (int)blockIdx.x * 128;
    int col0 = (int)blockIdx.y * 128;

    const float* W; float* C; int ldc;
    if (col0 < n0)           { W = W0; C = C0; ldc = n0; }
    else if (col0 < n0 + n1) { W = W1; C = C1; ldc = n1; col0 -= n0; }
    else                     { W = W2; C = C2; ldc = n2; col0 -= (n0 + n1); }

    const int lr = tid >> 2;          // 0..63
    const int lc = (tid & 3) << 2;    // 0,4,8,12
    const float* Ap = A + (size_t)(row0 + lr) * K + lc;
    const float* Bp = W + (size_t)(col0 + lr) * K + lc;

    float acc[8][8];
    #pragma unroll
    for (int i = 0; i < 8; ++i)
        #pragma unroll
        for (int j = 0; j < 8; ++j) acc[i][j] = 0.f;

    for (int k0 = 0; k0 < K; k0 += 16) {
        #pragma unroll
        for (int hh = 0; hh < 2; ++hh) {
            float4 av = *(const float4*)(Ap + (size_t)(hh * 64) * K + k0);
            float4 bv = *(const float4*)(Bp + (size_t)(hh * 64) * K + k0);
            const int r = lr + hh * 64;
            As[lc + 0][r] = av.x; As[lc + 1][r] = av.y;
            As[lc + 2][r] = av.z; As[lc + 3][r] = av.w;
            Bs[lc + 0][r] = bv.x; Bs[lc + 1][r] = bv.y;
            Bs[lc + 2][r] = bv.z; Bs[lc + 3][r] = bv.w;
        }
        __syncthreads();
        #pragma unroll
        for (int kk = 0; kk < 16; ++kk) {
            float a[8], b[8];
            *(float4*)&a[0] = *(const float4*)&As[kk][4 * ty];
            *(float4*)&a[4] = *(const float4*)&As[kk][64 + 4 * ty];
            *(float4*)&b[0] = *(const float4*)&Bs[kk][4 * tx];
            *(float4*)&b[4] = *(const float4*)&Bs[kk][64 + 4 * tx];
            #pragma unroll
            for (int i = 0; i < 8; ++i)
                #pragma unroll
                for (int j = 0; j < 8; ++j)
                    acc[i][j] = fmaf(a[i], b[j], acc[i][j]);
        }
        __syncthreads();
    }

    #pragma unroll
    for (int i = 0; i < 8; ++i) {
        const int r = row0 + 64 * (i >> 2) + 4 * ty + (i & 3);
        float* crow = C + (size_t)r * ldc + col0;
        float4 w0 = make_float4(acc[i][0], acc[i][1], acc[i][2], acc[i][3]);
        float4 w1 = make_float4(acc[i][4], acc[i][5], acc[i][6], acc[i][7]);
        *(float4*)(crow + 4 * tx) = w0;
        *(float4*)(crow + 64 + 4 * tx) = w1;
    }
}

// ---------------------------------------------------------------------------
// RoPE (q,k only) + unit LayerNorm (q,k,v) + q *= 256. One wave per
// 256-elem head-vector; rope partner d<->d+128 via __shfl_xor(.,32).
// Row id r = t*12 + hh, hh: 0..7=q heads, 8..9=k heads, 10..11=v heads.
// ---------------------------------------------------------------------------
__global__ __launch_bounds__(256) void rope_norm(
    float* __restrict__ qb, float* __restrict__ kb, float* __restrict__ vb)
{
    const int row  = (int)blockIdx.x * 4 + ((int)threadIdx.x >> 6);
    const int lane = (int)threadIdx.x & 63;
    const int t  = row / 12;
    const int hh = row - t * 12;
    const int pos = t & (SS - 1);

    float* ptr;
    bool dorope, isq;
    if (hh < 8)       { ptr = qb + ((size_t)t << 11) + (hh << 8);        dorope = true;  isq = true;  }
    else if (hh < 10) { ptr = kb + ((size_t)t << 9) + ((hh - 8) << 8);   dorope = true;  isq = false; }
    else              { ptr = vb + ((size_t)t << 9) + ((hh - 10) << 8);  dorope = false; isq = false; }

    float x[4];
    *(float4*)x = *(const float4*)(ptr + (lane << 2));

    if (dorope) {
        float oth[4];
        #pragma unroll
        for (int e = 0; e < 4; ++e) oth[e] = __shfl_xor(x[e], 32);
        #pragma unroll
        for (int e = 0; e < 4; ++e) {
            const int d = (lane << 2) + e;
            const int f = d & 127;
            // inv_freq = theta^(-f/128), fp64 for accuracy vs fp32 reference
            const float invf = (float)exp2(-(double)f * (19.931568569324174 / 128.0));
            const float ang = (float)pos * invf;
            float sv, cv;
            sincosf(ang, &sv, &cv);
            const float rot = (lane < 32) ? -oth[e] : oth[e];
            x[e] = fmaf(x[e], cv, rot * sv);
        }
    }

    float s1 = x[0] + x[1] + x[2] + x[3];
    #pragma unroll
    for (int off = 1; off < 64; off <<= 1) s1 += __shfl_xor(s1, off);
    const float mu = s1 * (1.0f / 256.0f);
    float y[4];
    float s2 = 0.f;
    #pragma unroll
    for (int e = 0; e < 4; ++e) { y[e] = x[e] - mu; s2 = fmaf(y[e], y[e], s2); }
    #pragma unroll
    for (int off = 1; off < 64; off <<= 1) s2 += __shfl_xor(s2, off);
    const float rstd = rsqrtf(s2 * (1.0f / 256.0f) + LEPS);
    const float sc = isq ? rstd * QSCALAR : rstd;
    #pragma unroll
    for (int e = 0; e < 4; ++e) y[e] *= sc;
    *(float4*)(ptr + (lane << 2)) = *(float4*)y;
}

// ---------------------------------------------------------------------------
// Per-(b, kv-head) column sum of V over all 2048 positions; needed because
// the reference's mask-before-softcap gives EVERY masked key (incl. future)
// weight e^(-30-m) in the softmax.
// ---------------------------------------------------------------------------
__global__ __launch_bounds__(256) void v_colsum(
    const float* __restrict__ vb, float* __restrict__ vs)
{
    const int bk = (int)blockIdx.x;      // 0..3 = b*2 + kvh
    const int b = bk >> 1, kvh = bk & 1;
    const int d = (int)threadIdx.x;
    const float* p = vb + ((size_t)b * SS << 9) + (kvh << 8) + d;
    float s = 0.f;
    for (int j = 0; j < SS; ++j) s += p[(size_t)j << 9];
    vs[(bk << 8) + d] = s;
}

// ---------------------------------------------------------------------------
// fp32 flash attention, 16 q-rows per block, 32-key chunks, online softmax.
// Exact reference semantics: in-window masked keys score exactly -30 and
// flow through softmax/PV; out-of-window keys added analytically via
// (Vsum_global - Vsum_visited) * e^(-30-m) and count*e^(-30-m) in Z.
// ---------------------------------------------------------------------------
__global__ __launch_bounds__(256) void attn_fwd(
    const float* __restrict__ qb, const float* __restrict__ kb,
    const float* __restrict__ vb, const float* __restrict__ vsum,
    float* __restrict__ ao)
{
    __shared__ float Qs[16][260];
    __shared__ float KVs[32][260];   // K chunk, then reused for V chunk
    __shared__ float Ps[16][36];
    __shared__ float al[16];
    __shared__ float mfin[16], lfin[16];

    const int tid = (int)threadIdx.x;
    const int bh = (int)blockIdx.y;
    const int b  = bh >> 3;
    const int h  = bh & 7;
    const int kvh = h >> 2;                 // GQA: rep=4
    const int q0 = (int)blockIdx.x * 16;

    const int tx = tid & 15, ty = tid >> 4;   // score-phase layout
    const int l  = tid & 63, w = tid >> 6;    // pv-phase layout
    const int rg = l >> 4;                    // row group 0..3
    const int dcol = (l & 15) << 2;           // 4 cols
    const int dq = w << 6;                    // wave's d-quarter

    // stage Q tile
    #pragma unroll
    for (int i = 0; i < 4; ++i) {
        int idx = tid + (i << 8);
        int r = idx >> 6, c = (idx & 63) << 2;
        *(float4*)&Qs[r][c] =
            *(const float4*)(qb + ((size_t)(b * SS + q0 + r) << 11) + (h << 8) + c);
    }

    float m_reg = -INFINITY, l_reg = 0.0f;
    float o_[4][4];
    float vs_[4];
    #pragma unroll
    for (int e = 0; e < 4; ++e) {
        vs_[e] = 0.f;
        o_[0][e] = o_[1][e] = o_[2][e] = o_[3][e] = 0.f;
    }

    const int ks   = (q0 >= SWIN) ? ((q0 - (SWIN - 1)) & ~31) : 0;
    const int kend = ((q0 + 15) & ~31) + 32;

    __syncthreads();

    for (int kc = ks; kc < kend; kc += 32) {
        // stage K chunk
        #pragma unroll
        for (int i = 0; i < 8; ++i) {
            int idx = tid + (i << 8);
            int r = idx >> 6, c = (idx & 63) << 2;
            *(float4*)&KVs[r][c] =
                *(const float4*)(kb + ((size_t)(b * SS + kc + r) << 9) + (kvh << 8) + c);
        }
        __syncthreads();

        // scores: thread (tx,ty) -> row ty, keys tx and tx+16 (2-way LDS max)
        float s0 = 0.f, s1 = 0.f;
        {
            const float* qp = &Qs[ty][0];
            const float* k0 = &KVs[tx][0];
            const float* k1 = &KVs[tx + 16][0];
            #pragma unroll 16
            for (int c4 = 0; c4 < 64; ++c4) {
                float4 qv = *(const float4*)(qp + (c4 << 2));
                float4 x0 = *(const float4*)(k0 + (c4 << 2));
                float4 x1 = *(const float4*)(k1 + (c4 << 2));
                s0 = fmaf(qv.x, x0.x, s0); s0 = fmaf(qv.y, x0.y, s0);
                s0 = fmaf(qv.z, x0.z, s0); s0 = fmaf(qv.w, x0.w, s0);
                s1 = fmaf(qv.x, x1.x, s1); s1 = fmaf(qv.y, x1.y, s1);
                s1 = fmaf(qv.z, x1.z, s1); s1 = fmaf(qv.w, x1.w, s1);
            }
        }
        const int iq = q0 + ty;
        const int j0 = kc + tx, j1 = kc + tx + 16;
        const bool ok0 = (j0 <= iq) && (j0 >= iq - (SWIN - 1));
        const bool ok1 = (j1 <= iq) && (j1 >= iq - (SWIN - 1));
        // scores/sqrt(256) then softcap; masked = tanh(-inf)*30 = -30 exactly
        s0 = ok0 ? SCAP * tanhf(s0 * (1.0f / (16.0f * SCAP))) : -SCAP;
        s1 = ok1 ? SCAP * tanhf(s1 * (1.0f / (16.0f * SCAP))) : -SCAP;

        float cm = fmaxf(s0, s1);
        #pragma unroll
        for (int off = 1; off <= 8; off <<= 1) cm = fmaxf(cm, __shfl_xor(cm, off));
        const float m_new = fmaxf(m_reg, cm);
        const float p0 = expf(s0 - m_new);
        const float p1 = expf(s1 - m_new);
        float rsum = p0 + p1;
        #pragma unroll
        for (int off = 1; off <= 8; off <<= 1) rsum += __shfl_xor(rsum, off);
        const float alpha = expf(m_reg - m_new);   // first chunk: exp(-inf)=0
        l_reg = l_reg * alpha + rsum;
        m_reg = m_new;
        Ps[ty][tx] = p0;
        Ps[ty][tx + 16] = p1;
        if (tx == 0) al[ty] = alpha;
        __syncthreads();

        // stage V chunk (overwrites K; all readers are past the barrier)
        #pragma unroll
        for (int i = 0; i < 8; ++i) {
            int idx = tid + (i << 8);
            int r = idx >> 6, c = (idx & 63) << 2;
            *(float4*)&KVs[r][c] =
                *(const float4*)(vb + ((size_t)(b * SS + kc + r) << 9) + (kvh << 8) + c);
        }
        __syncthreads();

        // PV: wave owns d-quarter, lane owns 4 rows x 4 cols
        {
            const float a0 = al[4 * rg + 0], a1 = al[4 * rg + 1];
            const float a2 = al[4 * rg + 2], a3 = al[4 * rg + 3];
            #pragma unroll
            for (int e = 0; e < 4; ++e) {
                o_[0][e] *= a0; o_[1][e] *= a1; o_[2][e] *= a2; o_[3][e] *= a3;
            }
            #pragma unroll
            for (int j4 = 0; j4 < 8; ++j4) {
                float p0r[4], p1r[4], p2r[4], p3r[4];
                *(float4*)p0r = *(const float4*)&Ps[4 * rg + 0][j4 << 2];
                *(float4*)p1r = *(const float4*)&Ps[4 * rg + 1][j4 << 2];
                *(float4*)p2r = *(const float4*)&Ps[4 * rg + 2][j4 << 2];
                *(float4*)p3r = *(const float4*)&Ps[4 * rg + 3][j4 << 2];
                #pragma unroll
                for (int e = 0; e < 4; ++e) {
                    float vv[4];
                    *(float4*)vv = *(const float4*)&KVs[(j4 << 2) + e][dq + dcol];
                    #pragma unroll
                    for (int c = 0; c < 4; ++c) {
                        vs_[c] += vv[c];   // visited-range V sum (weight 1)
                        o_[0][c] = fmaf(p0r[e], vv[c], o_[0][c]);
                        o_[1][c] = fmaf(p1r[e], vv[c], o_[1][c]);
                        o_[2][c] = fmaf(p2r[e], vv[c], o_[2][c]);
                        o_[3][c] = fmaf(p3r[e], vv[c], o_[3][c]);
                    }
                }
            }
        }
        __syncthreads();
    }

    if (tx == 0) { mfin[ty] = m_reg; lfin[ty] = l_reg; }
    __syncthreads();

    const float nout = (float)(SS - (kend - ks));   // keys never visited
    float vg[4];
    *(float4*)vg = *(const float4*)(vsum + ((size_t)(b * NKVH + kvh) << 8) + dq + dcol);

    #pragma unroll
    for (int i = 0; i < 4; ++i) {
        const int r = 4 * rg + i;
        const float m = mfin[r], lv = lfin[r];
        const float cw = expf(-SCAP - m);           // weight of unvisited masked keys
        const float inv = 1.0f / (lv + nout * cw);
        float outv[4];
        #pragma unroll
        for (int c = 0; c < 4; ++c)
            outv[c] = (o_[i][c] + cw * (vg[c] - vs_[c])) * inv;
        *(float4*)(ao + ((size_t)(b * SS + q0 + r) << 11) + (h << 8) + dq + dcol) =
            *(float4*)outv;
    }
}

// ---------------------------------------------------------------------------
extern "C" void kernel_launch(void* const* d_in, const int* in_sizes, int n_in,
                              void* d_out, int out_size, void* d_ws, size_t ws_size,
                              hipStream_t stream)
{
    (void)in_sizes; (void)n_in; (void)out_size; (void)ws_size;
    const float* hs = (const float*)d_in[0];
    const float* Wq = (const float*)d_in[1];
    const float* Wk = (const float*)d_in[2];
    const float* Wv = (const float*)d_in[3];
    const float* Wo = (const float*)d_in[4];
    float* out = (float*)d_out;

    // workspace layout (floats): q | k | v | attn_out | vsum  (~84 MB total)
    float* qb = (float*)d_ws;
    float* kb = qb + (size_t)4096 * 2048;
    float* vb = kb + (size_t)4096 * 512;
    float* ao = vb + (size_t)4096 * 512;
    float* vs = ao + (size_t)4096 * 2048;

    // 1) fused QKV projection: [4096,2048] @ [3072,2048]^T
    gemm_nt<<<dim3(32, 24), 256, 0, stream>>>(hs, Wq, Wk, Wv, qb, kb, vb,
                                              2048, 512, 512, 2048);
    // 2) RoPE + unit LayerNorm (+ q*256)
    rope_norm<<<dim3(12288), 256, 0, stream>>>(qb, kb, vb);
    // 3) global V column sums (for masked-key softmax contribution)
    v_colsum<<<dim3(4), 256, 0, stream>>>(vb, vs);
    // 4) sliding-window softcapped attention
    attn_fwd<<<dim3(128, 16), 256, 0, stream>>>(qb, kb, vb, vs, ao);
    // 5) output projection: [4096,2048] @ [2048,2048]^T
    gemm_nt<<<dim3(32, 16), 256, 0, stream>>>(ao, Wo, Wo, Wo, out, out, out,
                                              2048, 0, 0, 2048);
}

// Round 2
// 916.493 us; speedup vs baseline: 1.8815x; 1.8815x over previous
//
#include <hip/hip_runtime.h>
#include <hip/hip_bf16.h>
#include <math.h>

// Problem constants (Gemma3n attention block)
#define BB 2
#define SS 2048
#define HIDD 2048
#define NH 8
#define NKVH 2
#define HD 256
#define SWIN 512
#define QSCALAR 256.0f
#define LEPS 1e-6f
#define SCAP 30.0f

typedef short bfx8 __attribute__((ext_vector_type(8)));   // 8 bf16 = 4 VGPR
typedef float f32x4 __attribute__((ext_vector_type(4)));  // MFMA accum

__device__ __forceinline__ ushort f2bf(float f) {
    uint u = __float_as_uint(f);
    return (ushort)((u + 0x7fffu + ((u >> 16) & 1u)) >> 16);   // RNE
}
__device__ __forceinline__ float bf2f(ushort h) {
    return __uint_as_float(((uint)h) << 16);
}

// ---------------------------------------------------------------------------
// fp32 -> bf16 hi/lo split (hi = RNE(x), lo = RNE(x - hi)); 4 elems/thread
// ---------------------------------------------------------------------------
__global__ __launch_bounds__(256) void cvt_hilo(
    const float* __restrict__ x, ushort* __restrict__ hi, ushort* __restrict__ lo, int n4)
{
    int i = (int)blockIdx.x * 256 + (int)threadIdx.x;
    if (i >= n4) return;
    float4 v = ((const float4*)x)[i];
    ushort4 h, l;
    h.x = f2bf(v.x); l.x = f2bf(v.x - bf2f(h.x));
    h.y = f2bf(v.y); l.y = f2bf(v.y - bf2f(h.y));
    h.z = f2bf(v.z); l.z = f2bf(v.z - bf2f(h.z));
    h.w = f2bf(v.w); l.w = f2bf(v.w - bf2f(h.w));
    ((ushort4*)hi)[i] = h;
    ((ushort4*)lo)[i] = l;
}

__global__ __launch_bounds__(256) void cvt_hi(
    const float* __restrict__ x, ushort* __restrict__ hi, int n4)
{
    int i = (int)blockIdx.x * 256 + (int)threadIdx.x;
    if (i >= n4) return;
    float4 v = ((const float4*)x)[i];
    ushort4 h;
    h.x = f2bf(v.x); h.y = f2bf(v.y); h.z = f2bf(v.z); h.w = f2bf(v.w);
    ((ushort4*)hi)[i] = h;
}

// ---------------------------------------------------------------------------
// bf16 MFMA GEMM: C[M,N] = A[M,K] @ W[N,K]^T  (both row-major-K, "B^T input")
// 128x128 tile, BK=32, 256 thr = 4 waves (2x2 of 64x64), 16x16x32 MFMA,
// global_load_lds width=16 staging (m97 structure).
// SPLIT==3: A,B given as hi/lo bf16 pairs; acc = ah*bh + ah*bl + al*bh
//           (fp32-equivalent numerics, rel err ~3e-5).
// N is split into up to 3 column groups (fused QKV).
// ---------------------------------------------------------------------------
__device__ __forceinline__ void stage_tile(
    const ushort* __restrict__ g, int ldg, int grow0, int k0,
    ushort* lds, int w, int lane)
{
    #pragma unroll
    for (int j = 0; j < 2; ++j) {
        const int rr = w * 32 + j * 16;                        // 16 rows / issue
        const ushort* src = g + (size_t)(grow0 + rr + (lane >> 2)) * ldg
                              + k0 + ((lane & 3) << 3);
        __builtin_amdgcn_global_load_lds(
            (const __attribute__((address_space(1))) void*)src,
            (__attribute__((address_space(3))) void*)((char*)lds + rr * 64),
            16, 0, 0);
    }
}

template <int SPLIT>
__global__ __launch_bounds__(256) void gemm_bf16(
    const ushort* __restrict__ Ah, const ushort* __restrict__ Al,
    const ushort* __restrict__ Bh, const ushort* __restrict__ Bl,
    float* __restrict__ C0, float* __restrict__ C1, float* __restrict__ C2,
    int n0, int n1, int n2, int K)
{
    __shared__ __align__(16) ushort Ah_s[128 * 32];
    __shared__ __align__(16) ushort Bh_s[128 * 32];
    __shared__ __align__(16) ushort Al_s[SPLIT == 3 ? 128 * 32 : 8];
    __shared__ __align__(16) ushort Bl_s[SPLIT == 3 ? 128 * 32 : 8];

    const int tid  = (int)threadIdx.x;
    const int w    = tid >> 6;
    const int lane = tid & 63;
    const int wr = w >> 1, wc = w & 1;        // wave -> 64x64 quadrant
    const int lm = lane & 15, lk = lane >> 4; // frag row/col & k-block

    const int row0  = (int)blockIdx.x * 128;
    const int gcol0 = (int)blockIdx.y * 128;  // row index into combined W[N,K]

    int col0 = gcol0;
    float* C; int ldc;
    if (col0 < n0)           { C = C0; ldc = n0; }
    else if (col0 < n0 + n1) { C = C1; ldc = n1; col0 -= n0; }
    else                     { C = C2; ldc = n2; col0 -= (n0 + n1); }

    f32x4 acc[4][4];
    #pragma unroll
    for (int m = 0; m < 4; ++m)
        #pragma unroll
        for (int n = 0; n < 4; ++n) acc[m][n] = (f32x4)0.f;

    for (int k0 = 0; k0 < K; k0 += 32) {
        stage_tile(Ah, K, row0, k0, Ah_s, w, lane);
        stage_tile(Bh, K, gcol0, k0, Bh_s, w, lane);
        if constexpr (SPLIT == 3) {
            stage_tile(Al, K, row0, k0, Al_s, w, lane);
            stage_tile(Bl, K, gcol0, k0, Bl_s, w, lane);
        }
        __syncthreads();

        bfx8 ah[4], bh[4], al[4], bl[4];
        #pragma unroll
        for (int m = 0; m < 4; ++m) {
            const int ra = (wr * 64 + m * 16 + lm) * 32 + lk * 8;
            const int rb = (wc * 64 + m * 16 + lm) * 32 + lk * 8;
            ah[m] = *(const bfx8*)&Ah_s[ra];
            bh[m] = *(const bfx8*)&Bh_s[rb];
            if constexpr (SPLIT == 3) {
                al[m] = *(const bfx8*)&Al_s[ra];
                bl[m] = *(const bfx8*)&Bl_s[rb];
            }
        }
        #pragma unroll
        for (int m = 0; m < 4; ++m)
            #pragma unroll
            for (int n = 0; n < 4; ++n) {
                acc[m][n] = __builtin_amdgcn_mfma_f32_16x16x32_bf16(
                    ah[m], bh[n], acc[m][n], 0, 0, 0);
                if constexpr (SPLIT == 3) {
                    acc[m][n] = __builtin_amdgcn_mfma_f32_16x16x32_bf16(
                        ah[m], bl[n], acc[m][n], 0, 0, 0);
                    acc[m][n] = __builtin_amdgcn_mfma_f32_16x16x32_bf16(
                        al[m], bh[n], acc[m][n], 0, 0, 0);
                }
            }
        __syncthreads();
    }

    // C/D layout (m89-verified): col = lane&15, row = (lane>>4)*4 + reg
    #pragma unroll
    for (int m = 0; m < 4; ++m) {
        const int row = row0 + wr * 64 + m * 16 + lk * 4;
        #pragma unroll
        for (int n = 0; n < 4; ++n) {
            float* cp = C + (size_t)row * ldc + col0 + wc * 64 + n * 16 + lm;
            #pragma unroll
            for (int r = 0; r < 4; ++r) cp[(size_t)r * ldc] = acc[m][n][r];
        }
    }
}

// ---------------------------------------------------------------------------
// RoPE (q,k only) + unit LayerNorm (q,k,v) + q *= 256. One wave per
// 256-elem head-vector; rope partner d<->d+128 via __shfl_xor(.,32).
// ---------------------------------------------------------------------------
__global__ __launch_bounds__(256) void rope_norm(
    float* __restrict__ qb, float* __restrict__ kb, float* __restrict__ vb)
{
    const int row  = (int)blockIdx.x * 4 + ((int)threadIdx.x >> 6);
    const int lane = (int)threadIdx.x & 63;
    const int t  = row / 12;
    const int hh = row - t * 12;
    const int pos = t & (SS - 1);

    float* ptr;
    bool dorope, isq;
    if (hh < 8)       { ptr = qb + ((size_t)t << 11) + (hh << 8);        dorope = true;  isq = true;  }
    else if (hh < 10) { ptr = kb + ((size_t)t << 9) + ((hh - 8) << 8);   dorope = true;  isq = false; }
    else              { ptr = vb + ((size_t)t << 9) + ((hh - 10) << 8);  dorope = false; isq = false; }

    float x[4];
    *(float4*)x = *(const float4*)(ptr + (lane << 2));

    if (dorope) {
        float oth[4];
        #pragma unroll
        for (int e = 0; e < 4; ++e) oth[e] = __shfl_xor(x[e], 32);
        #pragma unroll
        for (int e = 0; e < 4; ++e) {
            const int d = (lane << 2) + e;
            const int f = d & 127;
            const float invf = (float)exp2(-(double)f * (19.931568569324174 / 128.0));
            const float ang = (float)pos * invf;
            float sv, cv;
            sincosf(ang, &sv, &cv);
            const float rot = (lane < 32) ? -oth[e] : oth[e];
            x[e] = fmaf(x[e], cv, rot * sv);
        }
    }

    float s1 = x[0] + x[1] + x[2] + x[3];
    #pragma unroll
    for (int off = 1; off < 64; off <<= 1) s1 += __shfl_xor(s1, off);
    const float mu = s1 * (1.0f / 256.0f);
    float y[4];
    float s2 = 0.f;
    #pragma unroll
    for (int e = 0; e < 4; ++e) { y[e] = x[e] - mu; s2 = fmaf(y[e], y[e], s2); }
    #pragma unroll
    for (int off = 1; off < 64; off <<= 1) s2 += __shfl_xor(s2, off);
    const float rstd = rsqrtf(s2 * (1.0f / 256.0f) + LEPS);
    const float sc = isq ? rstd * QSCALAR : rstd;
    #pragma unroll
    for (int e = 0; e < 4; ++e) y[e] *= sc;
    *(float4*)(ptr + (lane << 2)) = *(float4*)y;
}

// ---------------------------------------------------------------------------
// V column sums (two-stage, deterministic, parallel enough to not be
// latency-bound): needed for the masked-key e^(-30-m) softmax contribution.
// ---------------------------------------------------------------------------
__global__ __launch_bounds__(256) void v_part(
    const float* __restrict__ vb, float* __restrict__ vp)
{
    const int bk = (int)blockIdx.x >> 4, seg = (int)blockIdx.x & 15;
    const int b = bk >> 1, kvh = bk & 1;
    const float* p = vb + ((size_t)(b * SS + seg * 128) << 9) + (kvh << 8) + threadIdx.x;
    float s = 0.f;
    #pragma unroll 8
    for (int j = 0; j < 128; ++j) s += p[(size_t)j << 9];
    vp[((int)blockIdx.x << 8) + threadIdx.x] = s;
}

__global__ __launch_bounds__(256) void v_reduce(
    const float* __restrict__ vp, float* __restrict__ vs)
{
    const int bk = (int)blockIdx.x;
    float s = 0.f;
    #pragma unroll
    for (int seg = 0; seg < 16; ++seg) s += vp[((bk * 16 + seg) << 8) + threadIdx.x];
    vs[(bk << 8) + threadIdx.x] = s;
}

// ---------------------------------------------------------------------------
// fp32 flash attention (exact reference mask-before-softcap semantics),
// now emitting bf16 for the out-projection's A operand.
// ---------------------------------------------------------------------------
__global__ __launch_bounds__(256) void attn_fwd(
    const float* __restrict__ qb, const float* __restrict__ kb,
    const float* __restrict__ vb, const float* __restrict__ vsum,
    ushort* __restrict__ ao)
{
    __shared__ float Qs[16][260];
    __shared__ float KVs[32][260];
    __shared__ float Ps[16][36];
    __shared__ float al[16];
    __shared__ float mfin[16], lfin[16];

    const int tid = (int)threadIdx.x;
    const int bh = (int)blockIdx.y;
    const int b  = bh >> 3;
    const int h  = bh & 7;
    const int kvh = h >> 2;
    const int q0 = (int)blockIdx.x * 16;

    const int tx = tid & 15, ty = tid >> 4;
    const int l  = tid & 63, w = tid >> 6;
    const int rg = l >> 4;
    const int dcol = (l & 15) << 2;
    const int dq = w << 6;

    #pragma unroll
    for (int i = 0; i < 4; ++i) {
        int idx = tid + (i << 8);
        int r = idx >> 6, c = (idx & 63) << 2;
        *(float4*)&Qs[r][c] =
            *(const float4*)(qb + ((size_t)(b * SS + q0 + r) << 11) + (h << 8) + c);
    }

    float m_reg = -INFINITY, l_reg = 0.0f;
    float o_[4][4];
    float vs_[4];
    #pragma unroll
    for (int e = 0; e < 4; ++e) {
        vs_[e] = 0.f;
        o_[0][e] = o_[1][e] = o_[2][e] = o_[3][e] = 0.f;
    }

    const int ks   = (q0 >= SWIN) ? ((q0 - (SWIN - 1)) & ~31) : 0;
    const int kend = ((q0 + 15) & ~31) + 32;

    __syncthreads();

    for (int kc = ks; kc < kend; kc += 32) {
        #pragma unroll
        for (int i = 0; i < 8; ++i) {
            int idx = tid + (i << 8);
            int r = idx >> 6, c = (idx & 63) << 2;
            *(float4*)&KVs[r][c] =
                *(const float4*)(kb + ((size_t)(b * SS + kc + r) << 9) + (kvh << 8) + c);
        }
        __syncthreads();

        float s0 = 0.f, s1 = 0.f;
        {
            const float* qp = &Qs[ty][0];
            const float* k0 = &KVs[tx][0];
            const float* k1 = &KVs[tx + 16][0];
            #pragma unroll 16
            for (int c4 = 0; c4 < 64; ++c4) {
                float4 qv = *(const float4*)(qp + (c4 << 2));
                float4 x0 = *(const float4*)(k0 + (c4 << 2));
                float4 x1 = *(const float4*)(k1 + (c4 << 2));
                s0 = fmaf(qv.x, x0.x, s0); s0 = fmaf(qv.y, x0.y, s0);
                s0 = fmaf(qv.z, x0.z, s0); s0 = fmaf(qv.w, x0.w, s0);
                s1 = fmaf(qv.x, x1.x, s1); s1 = fmaf(qv.y, x1.y, s1);
                s1 = fmaf(qv.z, x1.z, s1); s1 = fmaf(qv.w, x1.w, s1);
            }
        }
        const int iq = q0 + ty;
        const int j0 = kc + tx, j1 = kc + tx + 16;
        const bool ok0 = (j0 <= iq) && (j0 >= iq - (SWIN - 1));
        const bool ok1 = (j1 <= iq) && (j1 >= iq - (SWIN - 1));
        s0 = ok0 ? SCAP * tanhf(s0 * (1.0f / (16.0f * SCAP))) : -SCAP;
        s1 = ok1 ? SCAP * tanhf(s1 * (1.0f / (16.0f * SCAP))) : -SCAP;

        float cm = fmaxf(s0, s1);
        #pragma unroll
        for (int off = 1; off <= 8; off <<= 1) cm = fmaxf(cm, __shfl_xor(cm, off));
        const float m_new = fmaxf(m_reg, cm);
        const float p0 = expf(s0 - m_new);
        const float p1 = expf(s1 - m_new);
        float rsum = p0 + p1;
        #pragma unroll
        for (int off = 1; off <= 8; off <<= 1) rsum += __shfl_xor(rsum, off);
        const float alpha = expf(m_reg - m_new);
        l_reg = l_reg * alpha + rsum;
        m_reg = m_new;
        Ps[ty][tx] = p0;
        Ps[ty][tx + 16] = p1;
        if (tx == 0) al[ty] = alpha;
        __syncthreads();

        #pragma unroll
        for (int i = 0; i < 8; ++i) {
            int idx = tid + (i << 8);
            int r = idx >> 6, c = (idx & 63) << 2;
            *(float4*)&KVs[r][c] =
                *(const float4*)(vb + ((size_t)(b * SS + kc + r) << 9) + (kvh << 8) + c);
        }
        __syncthreads();

        {
            const float a0 = al[4 * rg + 0], a1 = al[4 * rg + 1];
            const float a2 = al[4 * rg + 2], a3 = al[4 * rg + 3];
            #pragma unroll
            for (int e = 0; e < 4; ++e) {
                o_[0][e] *= a0; o_[1][e] *= a1; o_[2][e] *= a2; o_[3][e] *= a3;
            }
            #pragma unroll
            for (int j4 = 0; j4 < 8; ++j4) {
                float p0r[4], p1r[4], p2r[4], p3r[4];
                *(float4*)p0r = *(const float4*)&Ps[4 * rg + 0][j4 << 2];
                *(float4*)p1r = *(const float4*)&Ps[4 * rg + 1][j4 << 2];
                *(float4*)p2r = *(const float4*)&Ps[4 * rg + 2][j4 << 2];
                *(float4*)p3r = *(const float4*)&Ps[4 * rg + 3][j4 << 2];
                #pragma unroll
                for (int e = 0; e < 4; ++e) {
                    float vv[4];
                    *(float4*)vv = *(const float4*)&KVs[(j4 << 2) + e][dq + dcol];
                    #pragma unroll
                    for (int c = 0; c < 4; ++c) {
                        vs_[c] += vv[c];
                        o_[0][c] = fmaf(p0r[e], vv[c], o_[0][c]);
                        o_[1][c] = fmaf(p1r[e], vv[c], o_[1][c]);
                        o_[2][c] = fmaf(p2r[e], vv[c], o_[2][c]);
                        o_[3][c] = fmaf(p3r[e], vv[c], o_[3][c]);
                    }
                }
            }
        }
        __syncthreads();
    }

    if (tx == 0) { mfin[ty] = m_reg; lfin[ty] = l_reg; }
    __syncthreads();

    const float nout = (float)(SS - (kend - ks));
    float vg[4];
    *(float4*)vg = *(const float4*)(vsum + ((size_t)(b * NKVH + kvh) << 8) + dq + dcol);

    #pragma unroll
    for (int i = 0; i < 4; ++i) {
        const int r = 4 * rg + i;
        const float m = mfin[r], lv = lfin[r];
        const float cw = expf(-SCAP - m);
        const float inv = 1.0f / (lv + nout * cw);
        ushort4 st;
        st.x = f2bf((o_[i][0] + cw * (vg[0] - vs_[0])) * inv);
        st.y = f2bf((o_[i][1] + cw * (vg[1] - vs_[1])) * inv);
        st.z = f2bf((o_[i][2] + cw * (vg[2] - vs_[2])) * inv);
        st.w = f2bf((o_[i][3] + cw * (vg[3] - vs_[3])) * inv);
        *(ushort4*)(ao + ((size_t)(b * SS + q0 + r) << 11) + (h << 8) + dq + dcol) = st;
    }
}

// ---------------------------------------------------------------------------
extern "C" void kernel_launch(void* const* d_in, const int* in_sizes, int n_in,
                              void* d_out, int out_size, void* d_ws, size_t ws_size,
                              hipStream_t stream)
{
    (void)in_sizes; (void)n_in; (void)out_size; (void)ws_size;
    const float* hs = (const float*)d_in[0];
    const float* Wq = (const float*)d_in[1];
    const float* Wk = (const float*)d_in[2];
    const float* Wv = (const float*)d_in[3];
    const float* Wo = (const float*)d_in[4];
    float* out = (float*)d_out;

    // workspace layout (~134 MB)
    char* p = (char*)d_ws;
    float* qb   = (float*)p;  p += (size_t)4096 * 2048 * 4;
    float* kb   = (float*)p;  p += (size_t)4096 * 512 * 4;
    float* vb   = (float*)p;  p += (size_t)4096 * 512 * 4;
    float* vs   = (float*)p;  p += 4 * 256 * 4;
    float* vp   = (float*)p;  p += 64 * 256 * 4;
    ushort* ao  = (ushort*)p; p += (size_t)4096 * 2048 * 2;
    ushort* hsh = (ushort*)p; p += (size_t)4096 * 2048 * 2;
    ushort* hsl = (ushort*)p; p += (size_t)4096 * 2048 * 2;
    ushort* wkh = (ushort*)p; p += (size_t)3072 * 2048 * 2;
    ushort* wkl = (ushort*)p; p += (size_t)3072 * 2048 * 2;
    ushort* woh = (ushort*)p; p += (size_t)2048 * 2048 * 2;

    // 0) fp32 -> bf16 hi/lo conversions
    cvt_hilo<<<8192, 256, 0, stream>>>(hs, hsh, hsl, 2097152);
    cvt_hilo<<<4096, 256, 0, stream>>>(Wq, wkh, wkl, 1048576);
    cvt_hilo<<<1024, 256, 0, stream>>>(Wk, wkh + 4194304, wkl + 4194304, 262144);
    cvt_hilo<<<1024, 256, 0, stream>>>(Wv, wkh + 5242880, wkl + 5242880, 262144);
    cvt_hi  <<<4096, 256, 0, stream>>>(Wo, woh, 1048576);

    // 1) fused QKV projection, split-bf16 3-pass MFMA (fp32-equivalent)
    gemm_bf16<3><<<dim3(32, 24), 256, 0, stream>>>(
        hsh, hsl, wkh, wkl, qb, kb, vb, 2048, 512, 512, 2048);

    // 2) RoPE + unit LayerNorm (+ q*256), fp32
    rope_norm<<<12288, 256, 0, stream>>>(qb, kb, vb);

    // 3) global V column sums (two-stage)
    v_part  <<<64, 256, 0, stream>>>(vb, vp);
    v_reduce<<<4, 256, 0, stream>>>(vp, vs);

    // 4) sliding-window softcapped attention (fp32 math, bf16 output)
    attn_fwd<<<dim3(128, 16), 256, 0, stream>>>(qb, kb, vb, vs, ao);

    // 5) output projection, plain bf16 MFMA
    gemm_bf16<1><<<dim3(32, 16), 256, 0, stream>>>(
        ao, nullptr, woh, nullptr, out, out, out, 2048, 0, 0, 2048);
}

// Round 3
// 474.295 us; speedup vs baseline: 3.6357x; 1.9323x over previous
//
#include <hip/hip_runtime.h>
#include <hip/hip_bf16.h>
#include <math.h>

// Problem constants (Gemma3n attention block)
#define BB 2
#define SS 2048
#define HIDD 2048
#define NH 8
#define NKVH 2
#define HD 256
#define SWIN 512
#define QSCALAR 256.0f
#define LEPS 1e-6f
#define SCAP 30.0f

typedef short bfx8 __attribute__((ext_vector_type(8)));   // 8 bf16 = 4 VGPR
typedef float f32x4 __attribute__((ext_vector_type(4)));  // MFMA accum
typedef ushort u16x8 __attribute__((ext_vector_type(8)));

__device__ __forceinline__ ushort f2bf(float f) {
    uint u = __float_as_uint(f);
    return (ushort)((u + 0x7fffu + ((u >> 16) & 1u)) >> 16);   // RNE
}
__device__ __forceinline__ float bf2f(ushort h) {
    return __uint_as_float(((uint)h) << 16);
}

// ---------------------------------------------------------------------------
// fp32 -> bf16 hi/lo split
// ---------------------------------------------------------------------------
__global__ __launch_bounds__(256) void cvt_hilo(
    const float* __restrict__ x, ushort* __restrict__ hi, ushort* __restrict__ lo, int n4)
{
    int i = (int)blockIdx.x * 256 + (int)threadIdx.x;
    if (i >= n4) return;
    float4 v = ((const float4*)x)[i];
    ushort4 h, l;
    h.x = f2bf(v.x); l.x = f2bf(v.x - bf2f(h.x));
    h.y = f2bf(v.y); l.y = f2bf(v.y - bf2f(h.y));
    h.z = f2bf(v.z); l.z = f2bf(v.z - bf2f(h.z));
    h.w = f2bf(v.w); l.w = f2bf(v.w - bf2f(h.w));
    ((ushort4*)hi)[i] = h;
    ((ushort4*)lo)[i] = l;
}

__global__ __launch_bounds__(256) void cvt_hi(
    const float* __restrict__ x, ushort* __restrict__ hi, int n4)
{
    int i = (int)blockIdx.x * 256 + (int)threadIdx.x;
    if (i >= n4) return;
    float4 v = ((const float4*)x)[i];
    ushort4 h;
    h.x = f2bf(v.x); h.y = f2bf(v.y); h.z = f2bf(v.z); h.w = f2bf(v.w);
    ((ushort4*)hi)[i] = h;
}

// ---------------------------------------------------------------------------
// bf16 MFMA GEMM (m97 structure), SPLIT=3 for fp32-equivalent path
// ---------------------------------------------------------------------------
__device__ __forceinline__ void stage_tile(
    const ushort* __restrict__ g, int ldg, int grow0, int k0,
    ushort* lds, int w, int lane)
{
    #pragma unroll
    for (int j = 0; j < 2; ++j) {
        const int rr = w * 32 + j * 16;
        const ushort* src = g + (size_t)(grow0 + rr + (lane >> 2)) * ldg
                              + k0 + ((lane & 3) << 3);
        __builtin_amdgcn_global_load_lds(
            (const __attribute__((address_space(1))) void*)src,
            (__attribute__((address_space(3))) void*)((char*)lds + rr * 64),
            16, 0, 0);
    }
}

template <int SPLIT>
__global__ __launch_bounds__(256) void gemm_bf16(
    const ushort* __restrict__ Ah, const ushort* __restrict__ Al,
    const ushort* __restrict__ Bh, const ushort* __restrict__ Bl,
    float* __restrict__ C0, float* __restrict__ C1, float* __restrict__ C2,
    int n0, int n1, int n2, int K)
{
    __shared__ __align__(16) ushort Ah_s[128 * 32];
    __shared__ __align__(16) ushort Bh_s[128 * 32];
    __shared__ __align__(16) ushort Al_s[SPLIT == 3 ? 128 * 32 : 8];
    __shared__ __align__(16) ushort Bl_s[SPLIT == 3 ? 128 * 32 : 8];

    const int tid  = (int)threadIdx.x;
    const int w    = tid >> 6;
    const int lane = tid & 63;
    const int wr = w >> 1, wc = w & 1;
    const int lm = lane & 15, lk = lane >> 4;

    const int row0  = (int)blockIdx.x * 128;
    const int gcol0 = (int)blockIdx.y * 128;

    int col0 = gcol0;
    float* C; int ldc;
    if (col0 < n0)           { C = C0; ldc = n0; }
    else if (col0 < n0 + n1) { C = C1; ldc = n1; col0 -= n0; }
    else                     { C = C2; ldc = n2; col0 -= (n0 + n1); }

    f32x4 acc[4][4];
    #pragma unroll
    for (int m = 0; m < 4; ++m)
        #pragma unroll
        for (int n = 0; n < 4; ++n) acc[m][n] = (f32x4)0.f;

    for (int k0 = 0; k0 < K; k0 += 32) {
        stage_tile(Ah, K, row0, k0, Ah_s, w, lane);
        stage_tile(Bh, K, gcol0, k0, Bh_s, w, lane);
        if constexpr (SPLIT == 3) {
            stage_tile(Al, K, row0, k0, Al_s, w, lane);
            stage_tile(Bl, K, gcol0, k0, Bl_s, w, lane);
        }
        __syncthreads();

        bfx8 ah[4], bh[4], al[4], bl[4];
        #pragma unroll
        for (int m = 0; m < 4; ++m) {
            const int ra = (wr * 64 + m * 16 + lm) * 32 + lk * 8;
            const int rb = (wc * 64 + m * 16 + lm) * 32 + lk * 8;
            ah[m] = *(const bfx8*)&Ah_s[ra];
            bh[m] = *(const bfx8*)&Bh_s[rb];
            if constexpr (SPLIT == 3) {
                al[m] = *(const bfx8*)&Al_s[ra];
                bl[m] = *(const bfx8*)&Bl_s[rb];
            }
        }
        #pragma unroll
        for (int m = 0; m < 4; ++m)
            #pragma unroll
            for (int n = 0; n < 4; ++n) {
                acc[m][n] = __builtin_amdgcn_mfma_f32_16x16x32_bf16(
                    ah[m], bh[n], acc[m][n], 0, 0, 0);
                if constexpr (SPLIT == 3) {
                    acc[m][n] = __builtin_amdgcn_mfma_f32_16x16x32_bf16(
                        ah[m], bl[n], acc[m][n], 0, 0, 0);
                    acc[m][n] = __builtin_amdgcn_mfma_f32_16x16x32_bf16(
                        al[m], bh[n], acc[m][n], 0, 0, 0);
                }
            }
        __syncthreads();
    }

    #pragma unroll
    for (int m = 0; m < 4; ++m) {
        const int row = row0 + wr * 64 + m * 16 + lk * 4;
        #pragma unroll
        for (int n = 0; n < 4; ++n) {
            float* cp = C + (size_t)row * ldc + col0 + wc * 64 + n * 16 + lm;
            #pragma unroll
            for (int r = 0; r < 4; ++r) cp[(size_t)r * ldc] = acc[m][n][r];
        }
    }
}

// ---------------------------------------------------------------------------
// RoPE (q,k) + unit LayerNorm (q,k,v) + q*=256. Emits bf16 hi/lo for q,k;
// writes normalized v back in-place (fp32).
// ---------------------------------------------------------------------------
__global__ __launch_bounds__(256) void rope_norm(
    const float* __restrict__ qb, const float* __restrict__ kb, float* __restrict__ vb,
    ushort* __restrict__ Qh, ushort* __restrict__ Ql,
    ushort* __restrict__ Kh, ushort* __restrict__ Kl)
{
    const int row  = (int)blockIdx.x * 4 + ((int)threadIdx.x >> 6);
    const int lane = (int)threadIdx.x & 63;
    const int t  = row / 12;
    const int hh = row - t * 12;
    const int pos = t & (SS - 1);

    const float* src;
    size_t oidx;
    int mode;   // 0=q 1=k 2=v
    if (hh < 8)       { oidx = ((size_t)t << 11) + (hh << 8) + (lane << 2);        src = qb + oidx; mode = 0; }
    else if (hh < 10) { oidx = ((size_t)t << 9) + ((hh - 8) << 8) + (lane << 2);   src = kb + oidx; mode = 1; }
    else              { oidx = ((size_t)t << 9) + ((hh - 10) << 8) + (lane << 2);  src = vb + oidx; mode = 2; }

    float x[4];
    *(float4*)x = *(const float4*)src;

    if (mode < 2) {
        float oth[4];
        #pragma unroll
        for (int e = 0; e < 4; ++e) oth[e] = __shfl_xor(x[e], 32);
        #pragma unroll
        for (int e = 0; e < 4; ++e) {
            const int d = (lane << 2) + e;
            const int f = d & 127;
            const float invf = (float)exp2(-(double)f * (19.931568569324174 / 128.0));
            const float ang = (float)pos * invf;
            float sv, cv;
            sincosf(ang, &sv, &cv);
            const float rot = (lane < 32) ? -oth[e] : oth[e];
            x[e] = fmaf(x[e], cv, rot * sv);
        }
    }

    float s1 = x[0] + x[1] + x[2] + x[3];
    #pragma unroll
    for (int off = 1; off < 64; off <<= 1) s1 += __shfl_xor(s1, off);
    const float mu = s1 * (1.0f / 256.0f);
    float y[4];
    float s2 = 0.f;
    #pragma unroll
    for (int e = 0; e < 4; ++e) { y[e] = x[e] - mu; s2 = fmaf(y[e], y[e], s2); }
    #pragma unroll
    for (int off = 1; off < 64; off <<= 1) s2 += __shfl_xor(s2, off);
    const float rstd = rsqrtf(s2 * (1.0f / 256.0f) + LEPS);
    const float sc = (mode == 0) ? rstd * QSCALAR : rstd;
    #pragma unroll
    for (int e = 0; e < 4; ++e) y[e] *= sc;

    if (mode == 2) {
        *(float4*)(vb + oidx) = *(float4*)y;
    } else {
        ushort4 h4, l4;
        h4.x = f2bf(y[0]); l4.x = f2bf(y[0] - bf2f(h4.x));
        h4.y = f2bf(y[1]); l4.y = f2bf(y[1] - bf2f(h4.y));
        h4.z = f2bf(y[2]); l4.z = f2bf(y[2] - bf2f(h4.z));
        h4.w = f2bf(y[3]); l4.w = f2bf(y[3] - bf2f(h4.w));
        if (mode == 0) { *(ushort4*)(Qh + oidx) = h4; *(ushort4*)(Ql + oidx) = l4; }
        else           { *(ushort4*)(Kh + oidx) = h4; *(ushort4*)(Kl + oidx) = l4; }
    }
}

// ---------------------------------------------------------------------------
// V transpose to [bk][256 d][2048 s] bf16 hi/lo (PV B-operand layout)
// ---------------------------------------------------------------------------
__global__ __launch_bounds__(256) void vtrans(
    const float* __restrict__ vb, ushort* __restrict__ Vth, ushort* __restrict__ Vtl)
{
    __shared__ float T[256][33];
    const int bk = (int)blockIdx.x & 3, st = (int)blockIdx.x >> 2;  // 64 s-tiles of 32
    const int b = bk >> 1, kv = bk & 1;
    const int tid = (int)threadIdx.x;

    #pragma unroll
    for (int i = 0; i < 8; ++i) {
        int idx = tid + i * 256;              // 0..2047
        int s = idx >> 6, c4 = idx & 63;
        float4 v = *(const float4*)(vb + ((size_t)(b * 2048 + st * 32 + s)) * 512 + kv * 256 + c4 * 4);
        T[c4 * 4 + 0][s] = v.x; T[c4 * 4 + 1][s] = v.y;
        T[c4 * 4 + 2][s] = v.z; T[c4 * 4 + 3][s] = v.w;
    }
    __syncthreads();

    const int d = tid;
    ushort h[32], l[32];
    #pragma unroll
    for (int s = 0; s < 32; ++s) {
        float x = T[d][s];
        h[s] = f2bf(x);
        l[s] = f2bf(x - bf2f(h[s]));
    }
    size_t off = ((size_t)bk * 256 + d) * 2048 + st * 32;
    #pragma unroll
    for (int j = 0; j < 4; ++j) {
        *(u16x8*)(Vth + off + j * 8) = *(u16x8*)&h[j * 8];
        *(u16x8*)(Vtl + off + j * 8) = *(u16x8*)&l[j * 8];
    }
}

// ---------------------------------------------------------------------------
// V prefix sums at 32-key granularity: Vcum[bk][c][d] = sum_{s<32c} v[s][d]
// ---------------------------------------------------------------------------
__global__ __launch_bounds__(256) void vcum_part(
    const float* __restrict__ vb, float* __restrict__ Vpart)
{
    const int bk = (int)blockIdx.x >> 6, ch = (int)blockIdx.x & 63;
    const int b = bk >> 1, kv = bk & 1, d = (int)threadIdx.x;
    const float* p = vb + ((size_t)(b * 2048 + ch * 32)) * 512 + kv * 256 + d;
    float s = 0.f;
    #pragma unroll 8
    for (int j = 0; j < 32; ++j) s += p[(size_t)j * 512];
    Vpart[((size_t)(bk * 64 + ch)) * 256 + d] = s;
}

__global__ __launch_bounds__(256) void vcum_scan(
    const float* __restrict__ Vpart, float* __restrict__ Vcum)
{
    const int bk = (int)blockIdx.x, d = (int)threadIdx.x;
    float run = 0.f;
    Vcum[((size_t)(bk * 65)) * 256 + d] = 0.f;
    for (int c2 = 0; c2 < 64; ++c2) {
        run += Vpart[((size_t)(bk * 64 + c2)) * 256 + d];
        Vcum[((size_t)(bk * 65 + c2 + 1)) * 256 + d] = run;
    }
}

// ---------------------------------------------------------------------------
// MFMA flash attention, fp32-equivalent via hi/lo bf16 splits everywhere.
// 64 q-rows/block, 4 waves, 32-key chunks, exact mask-before-softcap
// semantics (in-range masked keys -> -30 through softmax; unvisited keys
// analytic via Vcum prefix sums).
// ---------------------------------------------------------------------------
__global__ __launch_bounds__(256, 2) void attn_mfma(
    const ushort* __restrict__ Qh, const ushort* __restrict__ Ql,
    const ushort* __restrict__ Kh, const ushort* __restrict__ Kl,
    const ushort* __restrict__ Vth, const ushort* __restrict__ Vtl,
    const float* __restrict__ Vcum, ushort* __restrict__ ao)
{
    // 64 KB static: K h/l (16+16), Vt h/l (16+16). P (8 KB) aliases Kh_s.
    __shared__ __align__(16) ushort Kh_s[32 * 256];
    __shared__ __align__(16) ushort Kl_s[32 * 256];
    __shared__ __align__(16) ushort Vh_s[256 * 32];
    __shared__ __align__(16) ushort Vl_s[256 * 32];

    const int tid = (int)threadIdx.x;
    const int w = tid >> 6, lane = tid & 63;
    const int c = lane & 15, lk = lane >> 4;
    const int bh = (int)blockIdx.y, b = bh >> 3, h = bh & 7, kv = h >> 2;
    const int bk = b * 2 + kv;
    const int q0 = (int)blockIdx.x * 64;

    ushort* Pw_h = Kh_s + w * 512;              // wave-private P hi (1KB)
    ushort* Pw_l = Kh_s + 2048 + w * 512;       // wave-private P lo

    // Q fragments from global bf16 hi/lo (A-operand: row=lane&15, k=lk*8+j)
    bfx8 qh[8], ql[8];
    {
        const size_t qoff = ((size_t)(b * 2048 + q0 + w * 16 + c)) * 2048 + h * 256 + lk * 8;
        #pragma unroll
        for (int ks = 0; ks < 8; ++ks) {
            qh[ks] = *(const bfx8*)(Qh + qoff + ks * 32);
            ql[ks] = *(const bfx8*)(Ql + qoff + ks * 32);
        }
    }

    f32x4 acc_o[16];
    #pragma unroll
    for (int i = 0; i < 16; ++i) acc_o[i] = (f32x4)0.f;
    float m_r[4] = {-INFINITY, -INFINITY, -INFINITY, -INFINITY};
    float l_r[4] = {0.f, 0.f, 0.f, 0.f};

    const int ks0  = (q0 >= SWIN) ? ((q0 - (SWIN - 1)) & ~31) : 0;
    const int kend = q0 + 64;

    for (int kc = ks0; kc < kend; kc += 32) {
        // ---- stage K (row-major swizzled) and Vt (transposed swizzled) ----
        #pragma unroll
        for (int ii = 0; ii < 4; ++ii) {
            const int islot = w * 4 + ii;
            {   // K: rows 512B, granule swizzle g' = g ^ (key&7)
                const int key = islot * 2 + (lane >> 5);
                const int g = (lane & 31) ^ (key & 7);
                const size_t src = ((size_t)(b * 2048 + kc + key)) * 512 + kv * 256 + g * 8;
                __builtin_amdgcn_global_load_lds(
                    (const __attribute__((address_space(1))) void*)(Kh + src),
                    (__attribute__((address_space(3))) void*)((char*)Kh_s + islot * 1024), 16, 0, 0);
                __builtin_amdgcn_global_load_lds(
                    (const __attribute__((address_space(1))) void*)(Kl + src),
                    (__attribute__((address_space(3))) void*)((char*)Kl_s + islot * 1024), 16, 0, 0);
            }
            {   // Vt: rows 64B, granule swizzle g' = g ^ (d&3)
                const int d = islot * 16 + (lane >> 2);
                const int g = (lane & 3) ^ (d & 3);
                const size_t src = ((size_t)(bk * 256 + d)) * 2048 + kc + g * 8;
                __builtin_amdgcn_global_load_lds(
                    (const __attribute__((address_space(1))) void*)(Vth + src),
                    (__attribute__((address_space(3))) void*)((char*)Vh_s + islot * 1024), 16, 0, 0);
                __builtin_amdgcn_global_load_lds(
                    (const __attribute__((address_space(1))) void*)(Vtl + src),
                    (__attribute__((address_space(3))) void*)((char*)Vl_s + islot * 1024), 16, 0, 0);
            }
        }
        __syncthreads();   // staging complete (includes vmcnt drain)

        // ---- QK^T: 3-way split, acc over 8 k-steps ----
        f32x4 acc_s[2] = {(f32x4)0.f, (f32x4)0.f};
        #pragma unroll
        for (int ks = 0; ks < 8; ++ks) {
            #pragma unroll
            for (int n = 0; n < 2; ++n) {
                const int key = n * 16 + c;
                const int gi = (ks * 4 + lk) ^ (key & 7);
                const bfx8 kfh = *(const bfx8*)&Kh_s[key * 256 + gi * 8];
                const bfx8 kfl = *(const bfx8*)&Kl_s[key * 256 + gi * 8];
                acc_s[n] = __builtin_amdgcn_mfma_f32_16x16x32_bf16(qh[ks], kfh, acc_s[n], 0, 0, 0);
                acc_s[n] = __builtin_amdgcn_mfma_f32_16x16x32_bf16(qh[ks], kfl, acc_s[n], 0, 0, 0);
                acc_s[n] = __builtin_amdgcn_mfma_f32_16x16x32_bf16(ql[ks], kfh, acc_s[n], 0, 0, 0);
            }
        }
        __syncthreads();   // all K reads done before P overwrites Kh_s region

        // ---- softmax (rows lk*4+r, replicated across 16-lane groups) ----
        float p[2][4];
        f32x4 alphav;
        #pragma unroll
        for (int r = 0; r < 4; ++r) {
            const int irow = q0 + w * 16 + lk * 4 + r;
            float s01[2];
            #pragma unroll
            for (int n = 0; n < 2; ++n) {
                float sp = acc_s[n][r] * (1.f / 16.f);
                sp = fminf(fmaxf(sp, -450.f), 450.f);
                float t = __expf(sp * (2.f / SCAP));
                float capv = SCAP - 2.f * SCAP / (t + 1.f);
                const int j = kc + n * 16 + c;
                s01[n] = (j <= irow && j > irow - SWIN) ? capv : -SCAP;
            }
            float cmx = fmaxf(s01[0], s01[1]);
            cmx = fmaxf(cmx, __shfl_xor(cmx, 1));
            cmx = fmaxf(cmx, __shfl_xor(cmx, 2));
            cmx = fmaxf(cmx, __shfl_xor(cmx, 4));
            cmx = fmaxf(cmx, __shfl_xor(cmx, 8));
            const float mn = fmaxf(m_r[r], cmx);
            const float p0 = __expf(s01[0] - mn);
            const float p1 = __expf(s01[1] - mn);
            float rs = p0 + p1;
            rs += __shfl_xor(rs, 1);
            rs += __shfl_xor(rs, 2);
            rs += __shfl_xor(rs, 4);
            rs += __shfl_xor(rs, 8);
            const float al = __expf(m_r[r] - mn);    // first chunk: exp(-inf)=0
            l_r[r] = l_r[r] * al + rs;
            m_r[r] = mn;
            alphav[r] = al;
            p[0][r] = p0; p[1][r] = p1;
        }
        #pragma unroll
        for (int i = 0; i < 16; ++i) acc_o[i] *= alphav;

        // ---- write P hi/lo to wave-private LDS (swizzled) ----
        #pragma unroll
        for (int n = 0; n < 2; ++n)
            #pragma unroll
            for (int r = 0; r < 4; ++r) {
                const int row = lk * 4 + r;
                const int gi = (2 * n + (c >> 3)) ^ (row & 3) ^ (row >> 2);
                const int idx = row * 32 + gi * 8 + (c & 7);
                const float pv = p[n][r];
                const ushort ph = f2bf(pv);
                Pw_h[idx] = ph;
                Pw_l[idx] = f2bf(pv - bf2f(ph));
            }
        asm volatile("s_waitcnt lgkmcnt(0)" ::: "memory");
        __builtin_amdgcn_sched_barrier(0);

        // ---- PV: 3-way split ----
        {
            const int gia = lk ^ (c & 3) ^ (c >> 2);
            const bfx8 pah = *(const bfx8*)&Pw_h[c * 32 + gia * 8];
            const bfx8 pal = *(const bfx8*)&Pw_l[c * 32 + gia * 8];
            #pragma unroll
            for (int nn = 0; nn < 16; ++nn) {
                const int d = nn * 16 + c;
                const int gv = lk ^ (d & 3);
                const bfx8 vfh = *(const bfx8*)&Vh_s[d * 32 + gv * 8];
                const bfx8 vfl = *(const bfx8*)&Vl_s[d * 32 + gv * 8];
                acc_o[nn] = __builtin_amdgcn_mfma_f32_16x16x32_bf16(pah, vfh, acc_o[nn], 0, 0, 0);
                acc_o[nn] = __builtin_amdgcn_mfma_f32_16x16x32_bf16(pah, vfl, acc_o[nn], 0, 0, 0);
                acc_o[nn] = __builtin_amdgcn_mfma_f32_16x16x32_bf16(pal, vfh, acc_o[nn], 0, 0, 0);
            }
        }
        __syncthreads();   // PV reads done before next chunk's staging
    }

    // ---- epilogue: unvisited masked keys analytically, then normalize ----
    const int cs = ks0 >> 5, ce = kend >> 5;
    const float nout = (float)(SS - (kend - ks0));
    float cw[4], inv[4];
    #pragma unroll
    for (int r = 0; r < 4; ++r) {
        cw[r] = __expf(-SCAP - m_r[r]);
        inv[r] = 1.f / (l_r[r] + nout * cw[r]);
    }
    #pragma unroll
    for (int nn = 0; nn < 16; ++nn) {
        const int d = nn * 16 + c;
        const size_t vco = ((size_t)bk * 65) * 256 + d;
        const float U = (Vcum[vco + (size_t)64 * 256] - Vcum[vco + (size_t)ce * 256])
                      + Vcum[vco + (size_t)cs * 256];
        #pragma unroll
        for (int r = 0; r < 4; ++r) {
            const int row = q0 + w * 16 + lk * 4 + r;
            const float ov = (acc_o[nn][r] + cw[r] * U) * inv[r];
            ao[((size_t)(b * 2048 + row)) * 2048 + h * 256 + d] = f2bf(ov);
        }
    }
}

// ---------------------------------------------------------------------------
extern "C" void kernel_launch(void* const* d_in, const int* in_sizes, int n_in,
                              void* d_out, int out_size, void* d_ws, size_t ws_size,
                              hipStream_t stream)
{
    (void)in_sizes; (void)n_in; (void)out_size; (void)ws_size;
    const float* hs = (const float*)d_in[0];
    const float* Wq = (const float*)d_in[1];
    const float* Wk = (const float*)d_in[2];
    const float* Wv = (const float*)d_in[3];
    const float* Wo = (const float*)d_in[4];
    float* out = (float*)d_out;

    const size_t MB = 1024 * 1024;
    char* p = (char*)d_ws;
    // region A/B: hs hi/lo, reused as Q hi/lo after QKV GEMM
    ushort* hsh = (ushort*)(p + 0 * MB);       // 16MB
    ushort* hsl = (ushort*)(p + 16 * MB);      // 16MB
    // region C: W_qkv hi, reused as [Kh | Kl | Vth]
    ushort* wkh = (ushort*)(p + 32 * MB);      // 12MB
    // region D: W_qkv lo, reused as [Vtl | Vcum | Vpart]
    ushort* wkl = (ushort*)(p + 44 * MB);      // 12MB
    ushort* woh = (ushort*)(p + 56 * MB);      // 8MB (persistent)
    float*  qb  = (float*)(p + 64 * MB);       // 32MB fp32 q, reused as ao
    float*  kb  = (float*)(p + 96 * MB);       // 8MB
    float*  vb  = (float*)(p + 104 * MB);      // 8MB
    // aliases
    ushort* Qh  = hsh;
    ushort* Ql  = hsl;
    ushort* Kh  = wkh;
    ushort* Kl  = wkh + 2097152;               // +4MB
    ushort* Vth = wkh + 4194304;               // +8MB
    ushort* Vtl = wkl;
    float*  Vcum  = (float*)(p + 44 * MB + 4 * MB);
    float*  Vpart = (float*)(p + 44 * MB + 5 * MB);
    ushort* ao  = (ushort*)qb;

    // 0) fp32 -> bf16 conversions
    cvt_hilo<<<8192, 256, 0, stream>>>(hs, hsh, hsl, 2097152);
    cvt_hilo<<<4096, 256, 0, stream>>>(Wq, wkh, wkl, 1048576);
    cvt_hilo<<<1024, 256, 0, stream>>>(Wk, wkh + 4194304, wkl + 4194304, 262144);
    cvt_hilo<<<1024, 256, 0, stream>>>(Wv, wkh + 5242880, wkl + 5242880, 262144);
    cvt_hi  <<<4096, 256, 0, stream>>>(Wo, woh, 1048576);

    // 1) fused QKV projection (split-bf16, fp32-equivalent)
    gemm_bf16<3><<<dim3(32, 24), 256, 0, stream>>>(
        hsh, hsl, wkh, wkl, qb, kb, vb, 2048, 512, 512, 2048);

    // 2) RoPE + unit LayerNorm; emit Q/K bf16 hi/lo, v fp32 in-place
    rope_norm<<<12288, 256, 0, stream>>>(qb, kb, vb, Qh, Ql, Kh, Kl);

    // 3) V transpose (hi/lo) + prefix sums
    vtrans   <<<256, 256, 0, stream>>>(vb, Vth, Vtl);
    vcum_part<<<256, 256, 0, stream>>>(vb, Vpart);
    vcum_scan<<<4, 256, 0, stream>>>(Vpart, Vcum);

    // 4) MFMA flash attention (fp32-equivalent hi/lo)
    attn_mfma<<<dim3(32, 16), 256, 0, stream>>>(Qh, Ql, Kh, Kl, Vth, Vtl, Vcum, ao);

    // 5) output projection (plain bf16)
    gemm_bf16<1><<<dim3(32, 16), 256, 0, stream>>>(
        ao, nullptr, woh, nullptr, out, out, out, 2048, 0, 0, 2048);
}

// Round 4
// 333.818 us; speedup vs baseline: 5.1656x; 1.4208x over previous
//
#include <hip/hip_runtime.h>
#include <hip/hip_bf16.h>
#include <math.h>

// Problem constants (Gemma3n attention block)
#define BB 2
#define SS 2048
#define HIDD 2048
#define NH 8
#define NKVH 2
#define HD 256
#define SWIN 512
#define QSCALAR 256.0f
#define LEPS 1e-6f
#define SCAP 30.0f
// exp(-60): weight of a masked key under the fixed m=30 softmax shift
#define EXPM60 8.75651076269652e-27f

typedef short bfx8 __attribute__((ext_vector_type(8)));   // 8 bf16 = 4 VGPR
typedef float f32x4 __attribute__((ext_vector_type(4)));  // MFMA accum
typedef ushort u16x8 __attribute__((ext_vector_type(8)));

__device__ __forceinline__ ushort f2bf(float f) {
    uint u = __float_as_uint(f);
    return (ushort)((u + 0x7fffu + ((u >> 16) & 1u)) >> 16);   // RNE
}
__device__ __forceinline__ float bf2f(ushort h) {
    return __uint_as_float(((uint)h) << 16);
}

// ---------------------------------------------------------------------------
// fp32 -> bf16 (plain)
// ---------------------------------------------------------------------------
__global__ __launch_bounds__(256) void cvt_hi(
    const float* __restrict__ x, ushort* __restrict__ hi, int n4)
{
    int i = (int)blockIdx.x * 256 + (int)threadIdx.x;
    if (i >= n4) return;
    float4 v = ((const float4*)x)[i];
    ushort4 h;
    h.x = f2bf(v.x); h.y = f2bf(v.y); h.z = f2bf(v.z); h.w = f2bf(v.w);
    ((ushort4*)hi)[i] = h;
}

// ---------------------------------------------------------------------------
// bf16 MFMA GEMM: C[M,N] = A[M,K] @ W[N,K]^T (m97 structure, 128x128, BK=32)
// N split into up to 3 column groups (fused QKV).
// ---------------------------------------------------------------------------
__device__ __forceinline__ void stage_tile(
    const ushort* __restrict__ g, int ldg, int grow0, int k0,
    ushort* lds, int w, int lane)
{
    #pragma unroll
    for (int j = 0; j < 2; ++j) {
        const int rr = w * 32 + j * 16;
        const ushort* src = g + (size_t)(grow0 + rr + (lane >> 2)) * ldg
                              + k0 + ((lane & 3) << 3);
        __builtin_amdgcn_global_load_lds(
            (const __attribute__((address_space(1))) void*)src,
            (__attribute__((address_space(3))) void*)((char*)lds + rr * 64),
            16, 0, 0);
    }
}

__global__ __launch_bounds__(256) void gemm_bf16(
    const ushort* __restrict__ Ah, const ushort* __restrict__ Bh,
    float* __restrict__ C0, float* __restrict__ C1, float* __restrict__ C2,
    int n0, int n1, int n2, int K)
{
    __shared__ __align__(16) ushort Ah_s[128 * 32];
    __shared__ __align__(16) ushort Bh_s[128 * 32];

    const int tid  = (int)threadIdx.x;
    const int w    = tid >> 6;
    const int lane = tid & 63;
    const int wr = w >> 1, wc = w & 1;
    const int lm = lane & 15, lk = lane >> 4;

    const int row0  = (int)blockIdx.x * 128;
    const int gcol0 = (int)blockIdx.y * 128;

    int col0 = gcol0;
    float* C; int ldc;
    if (col0 < n0)           { C = C0; ldc = n0; }
    else if (col0 < n0 + n1) { C = C1; ldc = n1; col0 -= n0; }
    else                     { C = C2; ldc = n2; col0 -= (n0 + n1); }

    f32x4 acc[4][4];
    #pragma unroll
    for (int m = 0; m < 4; ++m)
        #pragma unroll
        for (int n = 0; n < 4; ++n) acc[m][n] = (f32x4)0.f;

    for (int k0 = 0; k0 < K; k0 += 32) {
        stage_tile(Ah, K, row0, k0, Ah_s, w, lane);
        stage_tile(Bh, K, gcol0, k0, Bh_s, w, lane);
        __syncthreads();

        bfx8 ah[4], bh[4];
        #pragma unroll
        for (int m = 0; m < 4; ++m) {
            ah[m] = *(const bfx8*)&Ah_s[(wr * 64 + m * 16 + lm) * 32 + lk * 8];
            bh[m] = *(const bfx8*)&Bh_s[(wc * 64 + m * 16 + lm) * 32 + lk * 8];
        }
        #pragma unroll
        for (int m = 0; m < 4; ++m)
            #pragma unroll
            for (int n = 0; n < 4; ++n)
                acc[m][n] = __builtin_amdgcn_mfma_f32_16x16x32_bf16(
                    ah[m], bh[n], acc[m][n], 0, 0, 0);
        __syncthreads();
    }

    // C/D layout (m89-verified): col = lane&15, row = (lane>>4)*4 + reg
    #pragma unroll
    for (int m = 0; m < 4; ++m) {
        const int row = row0 + wr * 64 + m * 16 + lk * 4;
        #pragma unroll
        for (int n = 0; n < 4; ++n) {
            float* cp = C + (size_t)row * ldc + col0 + wc * 64 + n * 16 + lm;
            #pragma unroll
            for (int r = 0; r < 4; ++r) cp[(size_t)r * ldc] = acc[m][n][r];
        }
    }
}

// ---------------------------------------------------------------------------
// RoPE (q,k) + unit LayerNorm (q,k,v) + q*=256. Emits plain bf16 q,k;
// writes normalized v back in-place (fp32).
// ---------------------------------------------------------------------------
__global__ __launch_bounds__(256) void rope_norm(
    const float* __restrict__ qb, const float* __restrict__ kb, float* __restrict__ vb,
    ushort* __restrict__ Qo, ushort* __restrict__ Ko)
{
    const int row  = (int)blockIdx.x * 4 + ((int)threadIdx.x >> 6);
    const int lane = (int)threadIdx.x & 63;
    const int t  = row / 12;
    const int hh = row - t * 12;
    const int pos = t & (SS - 1);

    const float* src;
    size_t oidx;
    int mode;   // 0=q 1=k 2=v
    if (hh < 8)       { oidx = ((size_t)t << 11) + (hh << 8) + (lane << 2);        src = qb + oidx; mode = 0; }
    else if (hh < 10) { oidx = ((size_t)t << 9) + ((hh - 8) << 8) + (lane << 2);   src = kb + oidx; mode = 1; }
    else              { oidx = ((size_t)t << 9) + ((hh - 10) << 8) + (lane << 2);  src = vb + oidx; mode = 2; }

    float x[4];
    *(float4*)x = *(const float4*)src;

    if (mode < 2) {
        float oth[4];
        #pragma unroll
        for (int e = 0; e < 4; ++e) oth[e] = __shfl_xor(x[e], 32);
        #pragma unroll
        for (int e = 0; e < 4; ++e) {
            const int d = (lane << 2) + e;
            const int f = d & 127;
            const float invf = (float)exp2(-(double)f * (19.931568569324174 / 128.0));
            const float ang = (float)pos * invf;
            float sv, cv;
            sincosf(ang, &sv, &cv);
            const float rot = (lane < 32) ? -oth[e] : oth[e];
            x[e] = fmaf(x[e], cv, rot * sv);
        }
    }

    float s1 = x[0] + x[1] + x[2] + x[3];
    #pragma unroll
    for (int off = 1; off < 64; off <<= 1) s1 += __shfl_xor(s1, off);
    const float mu = s1 * (1.0f / 256.0f);
    float y[4];
    float s2 = 0.f;
    #pragma unroll
    for (int e = 0; e < 4; ++e) { y[e] = x[e] - mu; s2 = fmaf(y[e], y[e], s2); }
    #pragma unroll
    for (int off = 1; off < 64; off <<= 1) s2 += __shfl_xor(s2, off);
    const float rstd = rsqrtf(s2 * (1.0f / 256.0f) + LEPS);
    const float sc = (mode == 0) ? rstd * QSCALAR : rstd;
    #pragma unroll
    for (int e = 0; e < 4; ++e) y[e] *= sc;

    if (mode == 2) {
        *(float4*)(vb + oidx) = *(float4*)y;
    } else {
        ushort4 h4;
        h4.x = f2bf(y[0]); h4.y = f2bf(y[1]); h4.z = f2bf(y[2]); h4.w = f2bf(y[3]);
        if (mode == 0) *(ushort4*)(Qo + oidx) = h4;
        else           *(ushort4*)(Ko + oidx) = h4;
    }
}

// ---------------------------------------------------------------------------
// V transpose to [bk][256 d][2048 s] bf16 (PV B-operand layout)
// ---------------------------------------------------------------------------
__global__ __launch_bounds__(256) void vtrans(
    const float* __restrict__ vb, ushort* __restrict__ Vt)
{
    __shared__ float T[256][33];
    const int bk = (int)blockIdx.x & 3, st = (int)blockIdx.x >> 2;
    const int b = bk >> 1, kv = bk & 1;
    const int tid = (int)threadIdx.x;

    #pragma unroll
    for (int i = 0; i < 8; ++i) {
        int idx = tid + i * 256;
        int s = idx >> 6, c4 = idx & 63;
        float4 v = *(const float4*)(vb + ((size_t)(b * 2048 + st * 32 + s)) * 512 + kv * 256 + c4 * 4);
        T[c4 * 4 + 0][s] = v.x; T[c4 * 4 + 1][s] = v.y;
        T[c4 * 4 + 2][s] = v.z; T[c4 * 4 + 3][s] = v.w;
    }
    __syncthreads();

    const int d = tid;
    ushort h[32];
    #pragma unroll
    for (int s = 0; s < 32; ++s) h[s] = f2bf(T[d][s]);
    size_t off = ((size_t)bk * 256 + d) * 2048 + st * 32;
    #pragma unroll
    for (int j = 0; j < 4; ++j)
        *(u16x8*)(Vt + off + j * 8) = *(u16x8*)&h[j * 8];
}

// ---------------------------------------------------------------------------
// V prefix sums at 32-key granularity (fp32, exact)
// ---------------------------------------------------------------------------
__global__ __launch_bounds__(256) void vcum_part(
    const float* __restrict__ vb, float* __restrict__ Vpart)
{
    const int bk = (int)blockIdx.x >> 6, ch = (int)blockIdx.x & 63;
    const int b = bk >> 1, kv = bk & 1, d = (int)threadIdx.x;
    const float* p = vb + ((size_t)(b * 2048 + ch * 32)) * 512 + kv * 256 + d;
    float s = 0.f;
    #pragma unroll 8
    for (int j = 0; j < 32; ++j) s += p[(size_t)j * 512];
    Vpart[((size_t)(bk * 64 + ch)) * 256 + d] = s;
}

__global__ __launch_bounds__(256) void vcum_scan(
    const float* __restrict__ Vpart, float* __restrict__ Vcum)
{
    const int bk = (int)blockIdx.x, d = (int)threadIdx.x;
    float run = 0.f;
    Vcum[((size_t)(bk * 65)) * 256 + d] = 0.f;
    for (int c2 = 0; c2 < 64; ++c2) {
        run += Vpart[((size_t)(bk * 64 + c2)) * 256 + d];
        Vcum[((size_t)(bk * 65 + c2 + 1)) * 256 + d] = run;
    }
}

// ---------------------------------------------------------------------------
// stage one 32-key chunk of K (row-major, granule-swizzled) and Vt
// (transposed, granule-swizzled) into LDS via global_load_lds width=16
// ---------------------------------------------------------------------------
__device__ __forceinline__ void attn_stage(
    const ushort* __restrict__ Kb, const ushort* __restrict__ Vt,
    ushort* Ks, ushort* Vs, int b, int kv, int bk, int kc, int w, int lane)
{
    #pragma unroll
    for (int ii = 0; ii < 4; ++ii) {
        const int islot = w * 4 + ii;
        {   // K: 2 keys x 512B per slot; LDS pos (lane&31) holds granule g^(key&7)
            const int key = islot * 2 + (lane >> 5);
            const int g = (lane & 31) ^ (key & 7);
            const size_t src = ((size_t)(b * 2048 + kc + key)) * 512 + kv * 256 + g * 8;
            __builtin_amdgcn_global_load_lds(
                (const __attribute__((address_space(1))) void*)(Kb + src),
                (__attribute__((address_space(3))) void*)((char*)Ks + islot * 1024), 16, 0, 0);
        }
        {   // Vt: 16 d-rows x 64B per slot; LDS pos (lane&3) holds granule g^(d&3)
            const int d = islot * 16 + (lane >> 2);
            const int g = (lane & 3) ^ (d & 3);
            const size_t src = ((size_t)(bk * 256 + d)) * 2048 + kc + g * 8;
            __builtin_amdgcn_global_load_lds(
                (const __attribute__((address_space(1))) void*)(Vt + src),
                (__attribute__((address_space(3))) void*)((char*)Vs + islot * 1024), 16, 0, 0);
        }
    }
}

// ---------------------------------------------------------------------------
// MFMA flash attention, plain bf16, FIXED softmax shift m=30 (exact: post-cap
// scores bounded in [-30,30]); double-buffered K/V staging (2-phase recipe).
// Exact mask-before-softcap semantics: in-range masked keys weight e^-60
// through PV; unvisited keys analytic via Vcum prefix sums.
// ---------------------------------------------------------------------------
__global__ __launch_bounds__(256, 2) void attn_mfma(
    const ushort* __restrict__ Qb, const ushort* __restrict__ Kb,
    const ushort* __restrict__ Vt, const float* __restrict__ Vcum,
    ushort* __restrict__ ao)
{
    __shared__ __align__(16) ushort K_s[2][32 * 256];   // 16KB x2
    __shared__ __align__(16) ushort V_s[2][256 * 32];   // 16KB x2
    __shared__ __align__(16) ushort P_s[4][16 * 32];    // 1KB per wave

    const int tid = (int)threadIdx.x;
    const int w = tid >> 6, lane = tid & 63;
    const int c = lane & 15, lk = lane >> 4;
    const int bh = (int)blockIdx.y, b = bh >> 3, h = bh & 7, kv = h >> 2;
    const int bk = b * 2 + kv;
    const int q0 = (int)blockIdx.x * 64;

    const int ks0  = (q0 >= SWIN) ? (q0 - SWIN) : 0;   // == (q0-(SWIN-1)) & ~31
    const int kend = q0 + 64;
    const int nch  = (kend - ks0) >> 5;

    // Q fragments (A-operand: row = lane&15, k = lk*8 + j, per 32-k step)
    bfx8 qf[8];
    {
        const size_t qoff = ((size_t)(b * SS + q0 + w * 16 + c)) * 2048 + h * 256 + lk * 8;
        #pragma unroll
        for (int ks = 0; ks < 8; ++ks) qf[ks] = *(const bfx8*)(Qb + qoff + ks * 32);
    }

    f32x4 acc_o[16];
    #pragma unroll
    for (int i = 0; i < 16; ++i) acc_o[i] = (f32x4)0.f;
    float l_r[4] = {0.f, 0.f, 0.f, 0.f};   // lane-local partial denominators

    attn_stage(Kb, Vt, K_s[0], V_s[0], b, kv, bk, ks0, w, lane);
    __syncthreads();   // drains vmcnt(0): first chunk staged

    int cur = 0;
    for (int t = 0; t < nch; ++t) {
        const int kc = ks0 + t * 32;
        if (t + 1 < nch)   // issue next-chunk prefetch BEFORE compute (T3-lite)
            attn_stage(Kb, Vt, K_s[cur ^ 1], V_s[cur ^ 1], b, kv, bk, kc + 32, w, lane);

        // ---- QK^T: 16 MFMA ----
        f32x4 acc_s[2] = {(f32x4)0.f, (f32x4)0.f};
        #pragma unroll
        for (int ks = 0; ks < 8; ++ks) {
            #pragma unroll
            for (int n = 0; n < 2; ++n) {
                const int key = n * 16 + c;
                const int gi = (ks * 4 + lk) ^ (key & 7);
                const bfx8 kf = *(const bfx8*)&K_s[cur][key * 256 + gi * 8];
                acc_s[n] = __builtin_amdgcn_mfma_f32_16x16x32_bf16(qf[ks], kf, acc_s[n], 0, 0, 0);
            }
        }

        // ---- softcap + fixed-shift softmax + P write (no reductions!) ----
        #pragma unroll
        for (int r = 0; r < 4; ++r) {
            const int irow = q0 + w * 16 + lk * 4 + r;
            #pragma unroll
            for (int n = 0; n < 2; ++n) {
                const int j = kc + n * 16 + c;
                const float sp = acc_s[n][r] * (1.f / 16.f);
                // p = exp(30*tanh(sp/30) - 30) = exp(-60/(e^(2sp/30)+1));
                // handles +-inf/0 overflow of __expf correctly at the limits
                const float t1 = __expf(sp * (2.f / SCAP));
                const float pe = __expf(-2.f * SCAP / (t1 + 1.f));
                const bool ok = (j <= irow) && (j > irow - SWIN);
                const float pp = ok ? pe : EXPM60;
                l_r[r] += pp;
                const int row = lk * 4 + r;
                const int gi = (2 * n + (c >> 3)) ^ (row & 3) ^ (row >> 2);
                P_s[w][row * 32 + gi * 8 + (c & 7)] = f2bf(pp);
            }
        }
        asm volatile("s_waitcnt lgkmcnt(0)" ::: "memory");
        __builtin_amdgcn_sched_barrier(0);   // rule #18: fence MFMA hoisting

        // ---- PV: 16 MFMA ----
        {
            const int gia = lk ^ (c & 3) ^ (c >> 2);
            const bfx8 pa = *(const bfx8*)&P_s[w][c * 32 + gia * 8];
            #pragma unroll
            for (int nn = 0; nn < 16; ++nn) {
                const int d = nn * 16 + c;
                const int gv = lk ^ (d & 3);
                const bfx8 vf = *(const bfx8*)&V_s[cur][d * 32 + gv * 8];
                acc_o[nn] = __builtin_amdgcn_mfma_f32_16x16x32_bf16(pa, vf, acc_o[nn], 0, 0, 0);
            }
        }
        __syncthreads();   // prefetch landed (vmcnt0) + all waves done with cur
        cur ^= 1;
    }

    // ---- epilogue: reduce l across the 16-lane group; add unvisited keys ----
    #pragma unroll
    for (int r = 0; r < 4; ++r) {
        float s = l_r[r];
        s += __shfl_xor(s, 1); s += __shfl_xor(s, 2);
        s += __shfl_xor(s, 4); s += __shfl_xor(s, 8);
        l_r[r] = s;
    }
    const int cs = ks0 >> 5, ce = kend >> 5;
    const float nout = (float)(SS - (kend - ks0));
    float inv[4];
    #pragma unroll
    for (int r = 0; r < 4; ++r) inv[r] = 1.f / (l_r[r] + nout * EXPM60);

    #pragma unroll
    for (int nn = 0; nn < 16; ++nn) {
        const int d = nn * 16 + c;
        const size_t vco = ((size_t)bk * 65) * 256 + d;
        const float U = (Vcum[vco + (size_t)64 * 256] - Vcum[vco + (size_t)ce * 256])
                      + Vcum[vco + (size_t)cs * 256];
        #pragma unroll
        for (int r = 0; r < 4; ++r) {
            const int row = q0 + w * 16 + lk * 4 + r;
            const float ov = (acc_o[nn][r] + EXPM60 * U) * inv[r];
            ao[((size_t)(b * SS + row)) * 2048 + h * 256 + d] = f2bf(ov);
        }
    }
}

// ---------------------------------------------------------------------------
extern "C" void kernel_launch(void* const* d_in, const int* in_sizes, int n_in,
                              void* d_out, int out_size, void* d_ws, size_t ws_size,
                              hipStream_t stream)
{
    (void)in_sizes; (void)n_in; (void)out_size; (void)ws_size;
    const float* hs = (const float*)d_in[0];
    const float* Wq = (const float*)d_in[1];
    const float* Wk = (const float*)d_in[2];
    const float* Wv = (const float*)d_in[3];
    const float* Wo = (const float*)d_in[4];
    float* out = (float*)d_out;

    const size_t MiB = 1024 * 1024;
    char* p = (char*)d_ws;
    ushort* hsb = (ushort*)(p);               // 16 MiB (hs bf16; aliased by ao)
    ushort* wkb = (ushort*)(p + 16 * MiB);    // 12 MiB (Wqkv bf16; aliased by Vt/Vcum)
    ushort* wob = (ushort*)(p + 28 * MiB);    // 8 MiB  (Wo bf16, persistent)
    float*  qb  = (float*)(p + 36 * MiB);     // 32 MiB fp32 q
    float*  kb  = (float*)(p + 68 * MiB);     // 8 MiB fp32 k
    float*  vb  = (float*)(p + 76 * MiB);     // 8 MiB fp32 v
    ushort* Qo  = (ushort*)(p + 84 * MiB);    // 16 MiB bf16 q (post rope/norm)
    ushort* Ko  = (ushort*)(p + 100 * MiB);   // 4 MiB bf16 k
    // aliases into dead regions:
    ushort* ao    = hsb;                      // attn out bf16 (16 MiB)
    ushort* Vt    = wkb;                      // 4 MiB transposed V
    float*  Vcum  = (float*)(p + 20 * MiB);   // 260 KB
    float*  Vpart = (float*)(p + 21 * MiB);   // 256 KB

    // 0) fp32 -> bf16 conversions
    cvt_hi<<<8192, 256, 0, stream>>>(hs, hsb, 2097152);
    cvt_hi<<<4096, 256, 0, stream>>>(Wq, wkb, 1048576);
    cvt_hi<<<1024, 256, 0, stream>>>(Wk, wkb + 4194304, 262144);
    cvt_hi<<<1024, 256, 0, stream>>>(Wv, wkb + 5242880, 262144);
    cvt_hi<<<4096, 256, 0, stream>>>(Wo, wob, 1048576);

    // 1) fused QKV projection (plain bf16 MFMA)
    gemm_bf16<<<dim3(32, 24), 256, 0, stream>>>(
        hsb, wkb, qb, kb, vb, 2048, 512, 512, 2048);

    // 2) RoPE + unit LayerNorm; emit Q/K bf16, v fp32 in-place
    rope_norm<<<12288, 256, 0, stream>>>(qb, kb, vb, Qo, Ko);

    // 3) V transpose (bf16) + fp32 prefix sums
    vtrans   <<<256, 256, 0, stream>>>(vb, Vt);
    vcum_part<<<256, 256, 0, stream>>>(vb, Vpart);
    vcum_scan<<<4, 256, 0, stream>>>(Vpart, Vcum);

    // 4) MFMA flash attention (plain bf16, fixed-shift softmax, dbuf)
    attn_mfma<<<dim3(32, 16), 256, 0, stream>>>(Qo, Ko, Vt, Vcum, ao);

    // 5) output projection (plain bf16 MFMA)
    gemm_bf16<<<dim3(32, 16), 256, 0, stream>>>(
        ao, wob, out, out, out, 2048, 0, 0, 2048);
}

// Round 5
// 330.235 us; speedup vs baseline: 5.2217x; 1.0108x over previous
//
#include <hip/hip_runtime.h>
#include <hip/hip_bf16.h>
#include <math.h>

// Problem constants (Gemma3n attention block)
#define BB 2
#define SS 2048
#define HIDD 2048
#define NH 8
#define NKVH 2
#define HD 256
#define SWIN 512
#define QSCALAR 256.0f
#define LEPS 1e-6f
#define SCAP 30.0f
// exp(-60): weight of a masked key under the fixed m=30 softmax shift
#define EXPM60 8.75651076269652e-27f

typedef short bfx8 __attribute__((ext_vector_type(8)));   // 8 bf16 = 4 VGPR
typedef float f32x4 __attribute__((ext_vector_type(4)));  // MFMA accum
typedef ushort u16x8 __attribute__((ext_vector_type(8)));

__device__ __forceinline__ ushort f2bf(float f) {
    uint u = __float_as_uint(f);
    return (ushort)((u + 0x7fffu + ((u >> 16) & 1u)) >> 16);   // RNE
}
__device__ __forceinline__ float bf2f(ushort h) {
    return __uint_as_float(((uint)h) << 16);
}

// ---------------------------------------------------------------------------
// ALL fp32 -> bf16 conversions in ONE kernel (flat range dispatch).
// Ranges in float4 units: hs 2097152 | Wq 1048576 | Wk 262144 | Wv 262144
// | Wo 1048576; total 4718592 -> grid 18432 x 256 exactly.
// ---------------------------------------------------------------------------
__global__ __launch_bounds__(256) void cvt_all(
    const float* __restrict__ hs, const float* __restrict__ Wq,
    const float* __restrict__ Wk, const float* __restrict__ Wv,
    const float* __restrict__ Wo,
    ushort* __restrict__ hsb, ushort* __restrict__ wkb, ushort* __restrict__ wob)
{
    const int i = (int)blockIdx.x * 256 + (int)threadIdx.x;
    const float* s; ushort* d; int off;
    if (i < 2097152)      { s = hs; d = hsb;           off = i; }
    else if (i < 3145728) { s = Wq; d = wkb;           off = i - 2097152; }
    else if (i < 3407872) { s = Wk; d = wkb + 4194304; off = i - 3145728; }
    else if (i < 3670016) { s = Wv; d = wkb + 5242880; off = i - 3407872; }
    else                  { s = Wo; d = wob;           off = i - 3670016; }
    float4 v = ((const float4*)s)[off];
    ushort4 h;
    h.x = f2bf(v.x); h.y = f2bf(v.y); h.z = f2bf(v.z); h.w = f2bf(v.w);
    ((ushort4*)d)[off] = h;
}

// ---------------------------------------------------------------------------
// bf16 MFMA GEMM: C[M,N] = A[M,K] @ W[N,K]^T (m97 structure, 128x128, BK=32)
// UNCHANGED from round 4 (control; 8-phase port is next round's move).
// ---------------------------------------------------------------------------
__device__ __forceinline__ void stage_tile(
    const ushort* __restrict__ g, int ldg, int grow0, int k0,
    ushort* lds, int w, int lane)
{
    #pragma unroll
    for (int j = 0; j < 2; ++j) {
        const int rr = w * 32 + j * 16;
        const ushort* src = g + (size_t)(grow0 + rr + (lane >> 2)) * ldg
                              + k0 + ((lane & 3) << 3);
        __builtin_amdgcn_global_load_lds(
            (const __attribute__((address_space(1))) void*)src,
            (__attribute__((address_space(3))) void*)((char*)lds + rr * 64),
            16, 0, 0);
    }
}

__global__ __launch_bounds__(256) void gemm_bf16(
    const ushort* __restrict__ Ah, const ushort* __restrict__ Bh,
    float* __restrict__ C0, float* __restrict__ C1, float* __restrict__ C2,
    int n0, int n1, int n2, int K)
{
    __shared__ __align__(16) ushort Ah_s[128 * 32];
    __shared__ __align__(16) ushort Bh_s[128 * 32];

    const int tid  = (int)threadIdx.x;
    const int w    = tid >> 6;
    const int lane = tid & 63;
    const int wr = w >> 1, wc = w & 1;
    const int lm = lane & 15, lk = lane >> 4;

    const int row0  = (int)blockIdx.x * 128;
    const int gcol0 = (int)blockIdx.y * 128;

    int col0 = gcol0;
    float* C; int ldc;
    if (col0 < n0)           { C = C0; ldc = n0; }
    else if (col0 < n0 + n1) { C = C1; ldc = n1; col0 -= n0; }
    else                     { C = C2; ldc = n2; col0 -= (n0 + n1); }

    f32x4 acc[4][4];
    #pragma unroll
    for (int m = 0; m < 4; ++m)
        #pragma unroll
        for (int n = 0; n < 4; ++n) acc[m][n] = (f32x4)0.f;

    for (int k0 = 0; k0 < K; k0 += 32) {
        stage_tile(Ah, K, row0, k0, Ah_s, w, lane);
        stage_tile(Bh, K, gcol0, k0, Bh_s, w, lane);
        __syncthreads();

        bfx8 ah[4], bh[4];
        #pragma unroll
        for (int m = 0; m < 4; ++m) {
            ah[m] = *(const bfx8*)&Ah_s[(wr * 64 + m * 16 + lm) * 32 + lk * 8];
            bh[m] = *(const bfx8*)&Bh_s[(wc * 64 + m * 16 + lm) * 32 + lk * 8];
        }
        #pragma unroll
        for (int m = 0; m < 4; ++m)
            #pragma unroll
            for (int n = 0; n < 4; ++n)
                acc[m][n] = __builtin_amdgcn_mfma_f32_16x16x32_bf16(
                    ah[m], bh[n], acc[m][n], 0, 0, 0);
        __syncthreads();
    }

    // C/D layout (m89-verified): col = lane&15, row = (lane>>4)*4 + reg
    #pragma unroll
    for (int m = 0; m < 4; ++m) {
        const int row = row0 + wr * 64 + m * 16 + lk * 4;
        #pragma unroll
        for (int n = 0; n < 4; ++n) {
            float* cp = C + (size_t)row * ldc + col0 + wc * 64 + n * 16 + lm;
            #pragma unroll
            for (int r = 0; r < 4; ++r) cp[(size_t)r * ldc] = acc[m][n][r];
        }
    }
}

// ---------------------------------------------------------------------------
// RoPE (q,k) + unit LayerNorm (q,k,v) + q*=256. Emits plain bf16 q,k;
// writes normalized v back in-place (fp32). invf now fp32 exp2f (the fp64
// exp2 was ~2x the kernel's VALU cost for ~1e-7 rel accuracy we don't need:
// angle err ~1e-4 rad from sincosf reduction dominates either way, and is
// far below bf16 rounding of q/k).
// ---------------------------------------------------------------------------
__global__ __launch_bounds__(256) void rope_norm(
    const float* __restrict__ qb, const float* __restrict__ kb, float* __restrict__ vb,
    ushort* __restrict__ Qo, ushort* __restrict__ Ko)
{
    const int row  = (int)blockIdx.x * 4 + ((int)threadIdx.x >> 6);
    const int lane = (int)threadIdx.x & 63;
    const int t  = row / 12;
    const int hh = row - t * 12;
    const int pos = t & (SS - 1);

    const float* src;
    size_t oidx;
    int mode;   // 0=q 1=k 2=v
    if (hh < 8)       { oidx = ((size_t)t << 11) + (hh << 8) + (lane << 2);        src = qb + oidx; mode = 0; }
    else if (hh < 10) { oidx = ((size_t)t << 9) + ((hh - 8) << 8) + (lane << 2);   src = kb + oidx; mode = 1; }
    else              { oidx = ((size_t)t << 9) + ((hh - 10) << 8) + (lane << 2);  src = vb + oidx; mode = 2; }

    float x[4];
    *(float4*)x = *(const float4*)src;

    if (mode < 2) {
        float oth[4];
        #pragma unroll
        for (int e = 0; e < 4; ++e) oth[e] = __shfl_xor(x[e], 32);
        #pragma unroll
        for (int e = 0; e < 4; ++e) {
            const int d = (lane << 2) + e;
            const int f = d & 127;
            const float invf = exp2f(-(float)f * (19.931568569324174f / 128.0f));
            const float ang = (float)pos * invf;
            float sv, cv;
            __sincosf(ang, &sv, &cv);
            const float rot = (lane < 32) ? -oth[e] : oth[e];
            x[e] = fmaf(x[e], cv, rot * sv);
        }
    }

    float s1 = x[0] + x[1] + x[2] + x[3];
    #pragma unroll
    for (int off = 1; off < 64; off <<= 1) s1 += __shfl_xor(s1, off);
    const float mu = s1 * (1.0f / 256.0f);
    float y[4];
    float s2 = 0.f;
    #pragma unroll
    for (int e = 0; e < 4; ++e) { y[e] = x[e] - mu; s2 = fmaf(y[e], y[e], s2); }
    #pragma unroll
    for (int off = 1; off < 64; off <<= 1) s2 += __shfl_xor(s2, off);
    const float rstd = rsqrtf(s2 * (1.0f / 256.0f) + LEPS);
    const float sc = (mode == 0) ? rstd * QSCALAR : rstd;
    #pragma unroll
    for (int e = 0; e < 4; ++e) y[e] *= sc;

    if (mode == 2) {
        *(float4*)(vb + oidx) = *(float4*)y;
    } else {
        ushort4 h4;
        h4.x = f2bf(y[0]); h4.y = f2bf(y[1]); h4.z = f2bf(y[2]); h4.w = f2bf(y[3]);
        if (mode == 0) *(ushort4*)(Qo + oidx) = h4;
        else           *(ushort4*)(Ko + oidx) = h4;
    }
}

// ---------------------------------------------------------------------------
// V transpose to [bk][256 d][2048 s] bf16 + FUSED per-32-token partial column
// sums (same T[][] tile; kills the separate vcum_part kernel and its 8MB
// re-read).
// ---------------------------------------------------------------------------
__global__ __launch_bounds__(256) void vtrans(
    const float* __restrict__ vb, ushort* __restrict__ Vt, float* __restrict__ Vpart)
{
    __shared__ float T[256][33];
    const int bk = (int)blockIdx.x & 3, st = (int)blockIdx.x >> 2;  // st: 32-token chunk
    const int b = bk >> 1, kv = bk & 1;
    const int tid = (int)threadIdx.x;

    #pragma unroll
    for (int i = 0; i < 8; ++i) {
        int idx = tid + i * 256;
        int s = idx >> 6, c4 = idx & 63;
        float4 v = *(const float4*)(vb + ((size_t)(b * 2048 + st * 32 + s)) * 512 + kv * 256 + c4 * 4);
        T[c4 * 4 + 0][s] = v.x; T[c4 * 4 + 1][s] = v.y;
        T[c4 * 4 + 2][s] = v.z; T[c4 * 4 + 3][s] = v.w;
    }
    __syncthreads();

    const int d = tid;
    ushort h[32];
    float psum = 0.f;
    #pragma unroll
    for (int s = 0; s < 32; ++s) {
        const float x = T[d][s];
        h[s] = f2bf(x);
        psum += x;
    }
    size_t off = ((size_t)bk * 256 + d) * 2048 + st * 32;
    #pragma unroll
    for (int j = 0; j < 4; ++j)
        *(u16x8*)(Vt + off + j * 8) = *(u16x8*)&h[j * 8];
    Vpart[((size_t)(bk * 64 + st)) * 256 + d] = psum;
}

__global__ __launch_bounds__(256) void vcum_scan(
    const float* __restrict__ Vpart, float* __restrict__ Vcum)
{
    const int bk = (int)blockIdx.x, d = (int)threadIdx.x;
    float run = 0.f;
    Vcum[((size_t)(bk * 65)) * 256 + d] = 0.f;
    for (int c2 = 0; c2 < 64; ++c2) {
        run += Vpart[((size_t)(bk * 64 + c2)) * 256 + d];
        Vcum[((size_t)(bk * 65 + c2 + 1)) * 256 + d] = run;
    }
}

// ---------------------------------------------------------------------------
// stage one 32-key chunk of K (row-major, granule-swizzled) and Vt
// (transposed, granule-swizzled) into LDS via global_load_lds width=16
// ---------------------------------------------------------------------------
__device__ __forceinline__ void attn_stage(
    const ushort* __restrict__ Kb, const ushort* __restrict__ Vt,
    ushort* Ks, ushort* Vs, int b, int kv, int bk, int kc, int w, int lane)
{
    #pragma unroll
    for (int ii = 0; ii < 4; ++ii) {
        const int islot = w * 4 + ii;
        {   // K: 2 keys x 512B per slot; LDS pos (lane&31) holds granule g^(key&7)
            const int key = islot * 2 + (lane >> 5);
            const int g = (lane & 31) ^ (key & 7);
            const size_t src = ((size_t)(b * 2048 + kc + key)) * 512 + kv * 256 + g * 8;
            __builtin_amdgcn_global_load_lds(
                (const __attribute__((address_space(1))) void*)(Kb + src),
                (__attribute__((address_space(3))) void*)((char*)Ks + islot * 1024), 16, 0, 0);
        }
        {   // Vt: 16 d-rows x 64B per slot; LDS pos (lane&3) holds granule g^(d&3)
            const int d = islot * 16 + (lane >> 2);
            const int g = (lane & 3) ^ (d & 3);
            const size_t src = ((size_t)(bk * 256 + d)) * 2048 + kc + g * 8;
            __builtin_amdgcn_global_load_lds(
                (const __attribute__((address_space(1))) void*)(Vt + src),
                (__attribute__((address_space(3))) void*)((char*)Vs + islot * 1024), 16, 0, 0);
        }
    }
}

// ---------------------------------------------------------------------------
// MFMA flash attention v2: 128 q-rows/block (32/wave, 2 row-groups), so each
// K/V fragment read from LDS feeds TWO MFMAs -> LDS bytes per unit work
// halved vs v1 (the v1 bottleneck: LDS-throughput, 264KB/CU/chunk vs 310cy
// MFMA). Grid 16x16 = 256 blocks = 1 block/CU. Fixed softmax shift m=30
// (exact: post-cap scores bounded in [-30,30]); double-buffered staging;
// exact mask-before-softcap semantics (in-range masked keys weight e^-60
// through PV; unvisited keys analytic via Vcum prefix sums).
// ---------------------------------------------------------------------------
__global__ __launch_bounds__(256, 1) void attn_mfma(
    const ushort* __restrict__ Qb, const ushort* __restrict__ Kb,
    const ushort* __restrict__ Vt, const float* __restrict__ Vcum,
    ushort* __restrict__ ao)
{
    __shared__ __align__(16) ushort K_s[2][32 * 256];   // 16KB x2
    __shared__ __align__(16) ushort V_s[2][256 * 32];   // 16KB x2
    __shared__ __align__(16) ushort P_s[4][2][16 * 32]; // 1KB per wave per rg

    const int tid = (int)threadIdx.x;
    const int w = tid >> 6, lane = tid & 63;
    const int c = lane & 15, lk = lane >> 4;
    const int bh = (int)blockIdx.y, b = bh >> 3, h = bh & 7, kv = h >> 2;
    const int bk = b * 2 + kv;
    const int q0 = (int)blockIdx.x * 128;
    const int wq0 = q0 + w * 32;                 // wave's first q-row

    const int ks0  = (q0 >= SWIN) ? (q0 - SWIN) : 0;
    const int kend = q0 + 128;
    const int nch  = (kend - ks0) >> 5;

    // Q fragments: 2 row-groups x 8 k-steps (A-operand: row=lane&15, k=lk*8+j)
    bfx8 qf[2][8];
    #pragma unroll
    for (int rg = 0; rg < 2; ++rg) {
        const size_t qoff = ((size_t)(b * SS + wq0 + rg * 16 + c)) * 2048 + h * 256 + lk * 8;
        #pragma unroll
        for (int ks = 0; ks < 8; ++ks) qf[rg][ks] = *(const bfx8*)(Qb + qoff + ks * 32);
    }

    f32x4 acc_o[2][16];
    #pragma unroll
    for (int rg = 0; rg < 2; ++rg)
        #pragma unroll
        for (int i = 0; i < 16; ++i) acc_o[rg][i] = (f32x4)0.f;
    float l_r[2][4] = {{0.f, 0.f, 0.f, 0.f}, {0.f, 0.f, 0.f, 0.f}};

    attn_stage(Kb, Vt, K_s[0], V_s[0], b, kv, bk, ks0, w, lane);
    __syncthreads();   // drains vmcnt(0): first chunk staged

    int cur = 0;
    for (int t = 0; t < nch; ++t) {
        const int kc = ks0 + t * 32;
        if (t + 1 < nch)   // issue next-chunk prefetch BEFORE compute
            attn_stage(Kb, Vt, K_s[cur ^ 1], V_s[cur ^ 1], b, kv, bk, kc + 32, w, lane);

        // ---- QK^T: each kf feeds both row-groups (32 MFMA, 16 ds_read) ----
        f32x4 acc_s[2][2] = {{(f32x4)0.f, (f32x4)0.f}, {(f32x4)0.f, (f32x4)0.f}};
        #pragma unroll
        for (int ks = 0; ks < 8; ++ks) {
            #pragma unroll
            for (int n = 0; n < 2; ++n) {
                const int key = n * 16 + c;
                const int gi = (ks * 4 + lk) ^ (key & 7);
                const bfx8 kf = *(const bfx8*)&K_s[cur][key * 256 + gi * 8];
                acc_s[0][n] = __builtin_amdgcn_mfma_f32_16x16x32_bf16(qf[0][ks], kf, acc_s[0][n], 0, 0, 0);
                acc_s[1][n] = __builtin_amdgcn_mfma_f32_16x16x32_bf16(qf[1][ks], kf, acc_s[1][n], 0, 0, 0);
            }
        }

        // ---- softcap + fixed-shift softmax + P write (no reductions) ----
        #pragma unroll
        for (int rg = 0; rg < 2; ++rg)
            #pragma unroll
            for (int r = 0; r < 4; ++r) {
                const int irow = wq0 + rg * 16 + lk * 4 + r;
                #pragma unroll
                for (int n = 0; n < 2; ++n) {
                    const int j = kc + n * 16 + c;
                    const float sp = acc_s[rg][n][r] * (1.f / 16.f);
                    // p = exp(30*tanh(sp/30)-30) = exp(-60/(e^(2sp/30)+1));
                    // limits: sp->+inf -> 1, sp->-inf -> e^-60 (both exact)
                    const float t1 = __expf(sp * (2.f / SCAP));
                    const float pe = __expf(-2.f * SCAP / (t1 + 1.f));
                    const bool ok = (j <= irow) && (j > irow - SWIN);
                    const float pp = ok ? pe : EXPM60;
                    l_r[rg][r] += pp;
                    const int row = lk * 4 + r;
                    const int gi = (2 * n + (c >> 3)) ^ (row & 3) ^ (row >> 2);
                    P_s[w][rg][row * 32 + gi * 8 + (c & 7)] = f2bf(pp);
                }
            }
        asm volatile("s_waitcnt lgkmcnt(0)" ::: "memory");
        __builtin_amdgcn_sched_barrier(0);   // rule #18: fence MFMA hoisting

        // ---- PV: each vf feeds both row-groups (32 MFMA, 18 ds_read) ----
        {
            const int gia = lk ^ (c & 3) ^ (c >> 2);
            const bfx8 pa0 = *(const bfx8*)&P_s[w][0][c * 32 + gia * 8];
            const bfx8 pa1 = *(const bfx8*)&P_s[w][1][c * 32 + gia * 8];
            #pragma unroll
            for (int nn = 0; nn < 16; ++nn) {
                const int d = nn * 16 + c;
                const int gv = lk ^ (d & 3);
                const bfx8 vf = *(const bfx8*)&V_s[cur][d * 32 + gv * 8];
                acc_o[0][nn] = __builtin_amdgcn_mfma_f32_16x16x32_bf16(pa0, vf, acc_o[0][nn], 0, 0, 0);
                acc_o[1][nn] = __builtin_amdgcn_mfma_f32_16x16x32_bf16(pa1, vf, acc_o[1][nn], 0, 0, 0);
            }
        }
        __syncthreads();   // prefetch landed (vmcnt0) + all waves done with cur
        cur ^= 1;
    }

    // ---- epilogue: reduce l across 16-lane group; add unvisited keys ----
    #pragma unroll
    for (int rg = 0; rg < 2; ++rg)
        #pragma unroll
        for (int r = 0; r < 4; ++r) {
            float s = l_r[rg][r];
            s += __shfl_xor(s, 1); s += __shfl_xor(s, 2);
            s += __shfl_xor(s, 4); s += __shfl_xor(s, 8);
            l_r[rg][r] = s;
        }
    const int cs = ks0 >> 5, ce = kend >> 5;
    const float nout = (float)(SS - (kend - ks0));
    float inv[2][4];
    #pragma unroll
    for (int rg = 0; rg < 2; ++rg)
        #pragma unroll
        for (int r = 0; r < 4; ++r)
            inv[rg][r] = 1.f / (l_r[rg][r] + nout * EXPM60);

    #pragma unroll
    for (int nn = 0; nn < 16; ++nn) {
        const int d = nn * 16 + c;
        const size_t vco = ((size_t)bk * 65) * 256 + d;
        const float U = (Vcum[vco + (size_t)64 * 256] - Vcum[vco + (size_t)ce * 256])
                      + Vcum[vco + (size_t)cs * 256];
        #pragma unroll
        for (int rg = 0; rg < 2; ++rg)
            #pragma unroll
            for (int r = 0; r < 4; ++r) {
                const int row = wq0 + rg * 16 + lk * 4 + r;
                const float ov = (acc_o[rg][nn][r] + EXPM60 * U) * inv[rg][r];
                ao[((size_t)(b * SS + row)) * 2048 + h * 256 + d] = f2bf(ov);
            }
    }
}

// ---------------------------------------------------------------------------
extern "C" void kernel_launch(void* const* d_in, const int* in_sizes, int n_in,
                              void* d_out, int out_size, void* d_ws, size_t ws_size,
                              hipStream_t stream)
{
    (void)in_sizes; (void)n_in; (void)out_size; (void)ws_size;
    const float* hs = (const float*)d_in[0];
    const float* Wq = (const float*)d_in[1];
    const float* Wk = (const float*)d_in[2];
    const float* Wv = (const float*)d_in[3];
    const float* Wo = (const float*)d_in[4];
    float* out = (float*)d_out;

    const size_t MiB = 1024 * 1024;
    char* p = (char*)d_ws;
    ushort* hsb = (ushort*)(p);               // 16 MiB (hs bf16; aliased by ao)
    ushort* wkb = (ushort*)(p + 16 * MiB);    // 12 MiB (Wqkv bf16; aliased by Vt/Vcum)
    ushort* wob = (ushort*)(p + 28 * MiB);    // 8 MiB  (Wo bf16, persistent)
    float*  qb  = (float*)(p + 36 * MiB);     // 32 MiB fp32 q
    float*  kb  = (float*)(p + 68 * MiB);     // 8 MiB fp32 k
    float*  vb  = (float*)(p + 76 * MiB);     // 8 MiB fp32 v
    ushort* Qo  = (ushort*)(p + 84 * MiB);    // 16 MiB bf16 q (post rope/norm)
    ushort* Ko  = (ushort*)(p + 100 * MiB);   // 4 MiB bf16 k
    // aliases into dead regions (consumed before these are written):
    ushort* ao    = hsb;                      // attn out bf16 (16 MiB)
    ushort* Vt    = wkb;                      // 4 MiB transposed V
    float*  Vcum  = (float*)(p + 20 * MiB);   // 260 KB
    float*  Vpart = (float*)(p + 21 * MiB);   // 256 KB

    // 0) all fp32 -> bf16 conversions (one kernel)
    cvt_all<<<18432, 256, 0, stream>>>(hs, Wq, Wk, Wv, Wo, hsb, wkb, wob);

    // 1) fused QKV projection (plain bf16 MFMA)
    gemm_bf16<<<dim3(32, 24), 256, 0, stream>>>(
        hsb, wkb, qb, kb, vb, 2048, 512, 512, 2048);

    // 2) RoPE + unit LayerNorm; emit Q/K bf16, v fp32 in-place
    rope_norm<<<12288, 256, 0, stream>>>(qb, kb, vb, Qo, Ko);

    // 3) V transpose (bf16) + fused partial column sums, then tiny scan
    vtrans   <<<256, 256, 0, stream>>>(vb, Vt, Vpart);
    vcum_scan<<<4, 256, 0, stream>>>(Vpart, Vcum);

    // 4) MFMA flash attention v2 (128 q-rows/block)
    attn_mfma<<<dim3(16, 16), 256, 0, stream>>>(Qo, Ko, Vt, Vcum, ao);

    // 5) output projection (plain bf16 MFMA)
    gemm_bf16<<<dim3(32, 16), 256, 0, stream>>>(
        ao, wob, out, out, out, 2048, 0, 0, 2048);
}